// Round 1
// baseline (401.118 us; speedup 1.0000x reference)
//
#include <hip/hip_runtime.h>
#include <math.h>

#define B_N 4096
#define D_N 512
#define N_NEGS 100
#define N_DOM 8
#define TAU_F 1e-4f
#define EPS_F 1e-6f
#define REGW_F 1e-4f

// ---- workspace layout (float index offsets from ws base) ----
#define PHI_OFF 0                       // phi_aug [4096][512]
#define ACC_OFF (B_N * D_N)             // scalar accumulators
#define A_MSE 0
#define A_W2  1
#define A_B2  2
#define A_WH2 3
#define A_BH2 4
#define A_AUG 5
#define DEN_OFF (ACC_OFF + 16)          // den[4096]
#define NOM_OFF (DEN_OFF + B_N)         // nom[4096]

// ---------------------------------------------------------------------------
__global__ __launch_bounds__(256) void init_kernel(float* __restrict__ ws) {
    int i = blockIdx.x * 256 + threadIdx.x;
    if (i < 16 + 2 * B_N) ws[ACC_OFF + i] = 0.0f;
}

// ---------------------------------------------------------------------------
__device__ __forceinline__ float block_sum256(float v, float* sred) {
    #pragma unroll
    for (int m = 32; m; m >>= 1) v += __shfl_xor(v, m, 64);
    int lane = threadIdx.x & 63, wid = threadIdx.x >> 6;
    __syncthreads();                       // protect sred reuse
    if (lane == 0) sred[wid] = v;
    __syncthreads();
    float s = 0.0f;
    if (threadIdx.x == 0) s = sred[0] + sred[1] + sred[2] + sred[3];
    return s;                              // valid on thread 0
}

// mse sum, squared norms of W_e2 / b_e2 / W_head / b_head
__global__ __launch_bounds__(256) void small_reduce_kernel(
        const float* __restrict__ y_pred, const float* __restrict__ y_target,
        const float* __restrict__ W_e2, const float* __restrict__ b_e2,
        const float* __restrict__ W_head, const float* __restrict__ b_head,
        float* __restrict__ ws) {
    __shared__ float sred[4];
    int t = threadIdx.x;
    int job = blockIdx.y;
    if (job == 0) {                        // ||W_e2||^2 over 262144 elems
        float s = 0.0f;
        for (int i = blockIdx.x * 256 + t; i < D_N * D_N; i += gridDim.x * 256) {
            float w = W_e2[i]; s += w * w;
        }
        s = block_sum256(s, sred);
        if (t == 0) atomicAdd(&ws[ACC_OFF + A_W2], s);
    } else if (job == 1) {                 // sum (y_pred - y_target)^2
        float s = 0.0f;
        for (int i = blockIdx.x * 256 + t; i < B_N; i += gridDim.x * 256) {
            float d = y_pred[i] - y_target[i]; s += d * d;
        }
        s = block_sum256(s, sred);
        if (t == 0) atomicAdd(&ws[ACC_OFF + A_MSE], s);
    } else {                               // b_e2, W_head, b_head (block 0 only)
        if (blockIdx.x != 0) return;
        float v1 = b_e2[t], v2 = b_e2[t + 256];
        float s = block_sum256(v1 * v1 + v2 * v2, sred);
        if (t == 0) atomicAdd(&ws[ACC_OFF + A_B2], s);
        v1 = W_head[t]; v2 = W_head[t + 256];
        s = block_sum256(v1 * v1 + v2 * v2, sred);
        if (t == 0) {
            atomicAdd(&ws[ACC_OFF + A_WH2], s);
            atomicAdd(&ws[ACC_OFF + A_BH2], b_head[0] * b_head[0]);
        }
    }
}

// ---------------------------------------------------------------------------
// phi = (lmbda*e1 + (1-lmbda)*e1[mix]) @ W_e2 + b_e2   -- 64x64 tile, 4x4 micro
__global__ __launch_bounds__(256) void phi_kernel(
        const float* __restrict__ e1, const float* __restrict__ W,
        const float* __restrict__ bvec, const float* __restrict__ lmbda,
        const int* __restrict__ mix, float* __restrict__ phi) {
    __shared__ __align__(16) float As[32][64];   // [k][m]  (aug tile, transposed)
    __shared__ __align__(16) float Bs[32][64];   // [k][n]
    int rb = blockIdx.y * 64, cb = blockIdx.x * 64;
    int t = threadIdx.x, ty = t >> 4, tx = t & 15;
    int m  = t >> 2;
    int kq = (t & 3) * 8;
    int grow = rb + m;
    float lam = lmbda[grow];
    float oml = 1.0f - lam;
    int   mi  = mix[grow];
    const float* arow = e1 + (size_t)grow * D_N;
    const float* crow = e1 + (size_t)mi * D_N;
    int bk = t >> 3, bf = (t & 7) * 8;

    float acc[4][4] = {};
    for (int kk = 0; kk < D_N; kk += 32) {
        float4 a0 = *(const float4*)(arow + kk + kq);
        float4 a1 = *(const float4*)(arow + kk + kq + 4);
        float4 c0 = *(const float4*)(crow + kk + kq);
        float4 c1 = *(const float4*)(crow + kk + kq + 4);
        float4 w0 = *(const float4*)(W + (size_t)(kk + bk) * D_N + cb + bf);
        float4 w1 = *(const float4*)(W + (size_t)(kk + bk) * D_N + cb + bf + 4);
        __syncthreads();
        As[kq + 0][m] = lam * a0.x + oml * c0.x;
        As[kq + 1][m] = lam * a0.y + oml * c0.y;
        As[kq + 2][m] = lam * a0.z + oml * c0.z;
        As[kq + 3][m] = lam * a0.w + oml * c0.w;
        As[kq + 4][m] = lam * a1.x + oml * c1.x;
        As[kq + 5][m] = lam * a1.y + oml * c1.y;
        As[kq + 6][m] = lam * a1.z + oml * c1.z;
        As[kq + 7][m] = lam * a1.w + oml * c1.w;
        *(float4*)&Bs[bk][bf]     = w0;
        *(float4*)&Bs[bk][bf + 4] = w1;
        __syncthreads();
        #pragma unroll
        for (int k = 0; k < 32; ++k) {
            float4 a4 = *(const float4*)&As[k][ty * 4];
            float4 b4 = *(const float4*)&Bs[k][tx * 4];
            float a[4] = {a4.x, a4.y, a4.z, a4.w};
            float b[4] = {b4.x, b4.y, b4.z, b4.w};
            #pragma unroll
            for (int i = 0; i < 4; ++i)
                #pragma unroll
                for (int j = 0; j < 4; ++j) acc[i][j] += a[i] * b[j];
        }
    }
    float4 bb = *(const float4*)(bvec + cb + tx * 4);
    #pragma unroll
    for (int i = 0; i < 4; ++i) {
        float4 o = make_float4(acc[i][0] + bb.x, acc[i][1] + bb.y,
                               acc[i][2] + bb.z, acc[i][3] + bb.w);
        *(float4*)&phi[(size_t)(rb + ty * 4 + i) * D_N + cb + tx * 4] = o;
    }
}

// ---------------------------------------------------------------------------
// supp: Gram tile e2 @ e2^T, fused epilogue: den += exp(tau*s), nom += (diff dom)
__global__ __launch_bounds__(256) void supp_kernel(
        const float* __restrict__ e2, const int* __restrict__ tag,
        float* __restrict__ ws) {
    __shared__ __align__(16) float As[32][64];   // [k][m]
    __shared__ __align__(16) float Bs[32][64];   // [k][n]
    __shared__ int rt_s[64], ct_s[64];
    int rb = blockIdx.y * 64, cb = blockIdx.x * 64;
    int t = threadIdx.x, ty = t >> 4, tx = t & 15;
    if (t < 64) rt_s[t] = tag[rb + t];
    else if (t < 128) ct_s[t - 64] = tag[cb + t - 64];
    int m  = t >> 2;
    int kq = (t & 3) * 8;
    const float* arow = e2 + (size_t)(rb + m) * D_N;
    const float* brow = e2 + (size_t)(cb + m) * D_N;

    float acc[4][4] = {};
    for (int kk = 0; kk < D_N; kk += 32) {
        float4 a0 = *(const float4*)(arow + kk + kq);
        float4 a1 = *(const float4*)(arow + kk + kq + 4);
        float4 b0 = *(const float4*)(brow + kk + kq);
        float4 b1 = *(const float4*)(brow + kk + kq + 4);
        __syncthreads();
        As[kq + 0][m] = a0.x;  As[kq + 1][m] = a0.y;
        As[kq + 2][m] = a0.z;  As[kq + 3][m] = a0.w;
        As[kq + 4][m] = a1.x;  As[kq + 5][m] = a1.y;
        As[kq + 6][m] = a1.z;  As[kq + 7][m] = a1.w;
        Bs[kq + 0][m] = b0.x;  Bs[kq + 1][m] = b0.y;
        Bs[kq + 2][m] = b0.z;  Bs[kq + 3][m] = b0.w;
        Bs[kq + 4][m] = b1.x;  Bs[kq + 5][m] = b1.y;
        Bs[kq + 6][m] = b1.z;  Bs[kq + 7][m] = b1.w;
        __syncthreads();
        #pragma unroll
        for (int k = 0; k < 32; ++k) {
            float4 a4 = *(const float4*)&As[k][ty * 4];
            float4 b4 = *(const float4*)&Bs[k][tx * 4];
            float a[4] = {a4.x, a4.y, a4.z, a4.w};
            float b[4] = {b4.x, b4.y, b4.z, b4.w};
            #pragma unroll
            for (int i = 0; i < 4; ++i)
                #pragma unroll
                for (int j = 0; j < 4; ++j) acc[i][j] += a[i] * b[j];
        }
    }
    // epilogue: exp row-sums
    float den[4] = {}, nom[4] = {};
    int rt[4];
    #pragma unroll
    for (int i = 0; i < 4; ++i) rt[i] = rt_s[ty * 4 + i];
    #pragma unroll
    for (int j = 0; j < 4; ++j) {
        int ct = ct_s[tx * 4 + j];
        #pragma unroll
        for (int i = 0; i < 4; ++i) {
            float v = expf(TAU_F * acc[i][j]);
            den[i] += v;
            if (rt[i] != ct) nom[i] += v;
        }
    }
    #pragma unroll
    for (int i = 0; i < 4; ++i) {
        float d = den[i], n = nom[i];
        #pragma unroll
        for (int mm = 8; mm; mm >>= 1) {
            d += __shfl_xor(d, mm, 16);
            n += __shfl_xor(n, mm, 16);
        }
        if (tx == 0) {
            atomicAdd(&ws[DEN_OFF + rb + ty * 4 + i], d);
            atomicAdd(&ws[NOM_OFF + rb + ty * 4 + i], n);
        }
    }
}

// ---------------------------------------------------------------------------
// aug: per row j, pos = exp(tau * e2_j.phi_j), neg_k = exp(tau * e2_j.phi_neg)
__global__ __launch_bounds__(256) void aug_kernel(
        const float* __restrict__ e2, const float* __restrict__ phi,
        const int* __restrict__ neg_idx, float* __restrict__ ws) {
    __shared__ float e2s[D_N];
    __shared__ float wsum[4];
    __shared__ float wpos;
    int j = blockIdx.x;
    int t = threadIdx.x, lane = t & 63, w = t >> 6;
    e2s[t]       = e2[(size_t)j * D_N + t];
    e2s[t + 256] = e2[(size_t)j * D_N + t + 256];
    __syncthreads();
    float negsum = 0.0f, pos = 0.0f;
    for (int item = w; item < 1 + N_NEGS; item += 4) {
        int tgt = (item == 0) ? j : neg_idx[(size_t)j * N_NEGS + item - 1];
        const float* p = phi + (size_t)tgt * D_N;
        float s = 0.0f;
        #pragma unroll
        for (int e = 0; e < 8; ++e) s += e2s[lane + 64 * e] * p[lane + 64 * e];
        #pragma unroll
        for (int mm = 32; mm; mm >>= 1) s += __shfl_xor(s, mm, 64);
        float v = expf(TAU_F * s);
        if (item == 0) pos = v; else negsum += v;
    }
    if (lane == 0) wsum[w] = negsum;
    if (t == 0) wpos = pos;
    __syncthreads();
    if (t == 0) {
        float ns = wsum[0] + wsum[1] + wsum[2] + wsum[3];
        float L = logf(wpos / (EPS_F + wpos + ns));
        if (L == L) atomicAdd(&ws[ACC_OFF + A_AUG], L);   // skip NaN terms
    }
}

// ---------------------------------------------------------------------------
__global__ __launch_bounds__(256) void finalize_kernel(
        const float* __restrict__ ws, const int* __restrict__ tag,
        float* __restrict__ out) {
    __shared__ int cnt[N_DOM];
    __shared__ float sred[4];
    int t = threadIdx.x;
    if (t < N_DOM) cnt[t] = 0;
    __syncthreads();
    for (int i = t; i < B_N; i += 256) atomicAdd(&cnt[tag[i]], 1);
    __syncthreads();
    float local = 0.0f;
    for (int i = t; i < B_N; i += 256) {
        float den = ws[DEN_OFF + i], nom = ws[NOM_OFF + i];
        float L = logf(nom / (den + EPS_F));
        bool valid = (cnt[tag[i]] < B_N) && (L == L);
        if (valid) local += L;
    }
    float s = block_sum256(local, sred);
    if (t == 0) {
        out[0] = ws[ACC_OFF + A_MSE] / (float)B_N;
        out[1] = REGW_F * (sqrtf(ws[ACC_OFF + A_W2]) + sqrtf(ws[ACC_OFF + A_B2]) +
                           sqrtf(ws[ACC_OFF + A_WH2]) + sqrtf(ws[ACC_OFF + A_BH2]));
        out[2] = -ws[ACC_OFF + A_AUG] / (float)B_N;
        out[3] = -s / (float)B_N;
    }
}

// ---------------------------------------------------------------------------
extern "C" void kernel_launch(void* const* d_in, const int* in_sizes, int n_in,
                              void* d_out, int out_size, void* d_ws, size_t ws_size,
                              hipStream_t stream) {
    const float* e1       = (const float*)d_in[0];
    const float* e2       = (const float*)d_in[1];
    const float* y_pred   = (const float*)d_in[2];
    const float* y_target = (const float*)d_in[3];
    const float* W_e2     = (const float*)d_in[4];
    const float* b_e2     = (const float*)d_in[5];
    const float* W_head   = (const float*)d_in[6];
    const float* b_head   = (const float*)d_in[7];
    const float* lmbda    = (const float*)d_in[8];
    const int*   mix_idx  = (const int*)d_in[9];
    const int*   neg_idx  = (const int*)d_in[10];
    const int*   dtag     = (const int*)d_in[11];
    float* ws  = (float*)d_ws;
    float* out = (float*)d_out;

    init_kernel<<<dim3((16 + 2 * B_N + 255) / 256), dim3(256), 0, stream>>>(ws);
    small_reduce_kernel<<<dim3(128, 3), dim3(256), 0, stream>>>(
        y_pred, y_target, W_e2, b_e2, W_head, b_head, ws);
    phi_kernel<<<dim3(D_N / 64, B_N / 64), dim3(256), 0, stream>>>(
        e1, W_e2, b_e2, lmbda, mix_idx, ws + PHI_OFF);
    supp_kernel<<<dim3(B_N / 64, B_N / 64), dim3(256), 0, stream>>>(e2, dtag, ws);
    aug_kernel<<<dim3(B_N), dim3(256), 0, stream>>>(e2, ws + PHI_OFF, neg_idx, ws);
    finalize_kernel<<<dim3(1), dim3(256), 0, stream>>>(ws, dtag, out);
}

// Round 2
// 161.829 us; speedup vs baseline: 2.4787x; 2.4787x over previous
//
#include <hip/hip_runtime.h>
#include <hip/hip_bf16.h>
#include <math.h>

#define B_N 4096
#define D_N 512
#define N_NEGS 100
#define N_DOM 8
#define TAU_F 1e-4f
#define EPS_F 1e-6f
#define REGW_F 1e-4f

typedef __attribute__((ext_vector_type(8))) short bf16x8;
typedef __attribute__((ext_vector_type(4))) float f32x4;

// ---- workspace layout (float index offsets). Total = 8,421,440 bytes,
// exactly the round-1 proven footprint.
#define PHIB_F 0                       // bf16 phi [4096][512]  (4 MB)
#define X_F    (B_N * D_N / 2)         // region X: Wtb (phi phase) then e2b (supp phase)
#define ACC_F  (B_N * D_N)             // scalar accumulators
#define A_MSE 0
#define A_W2  1
#define A_B2  2
#define A_WH2 3
#define A_BH2 4
#define A_AUG 5
#define DEN_F (ACC_F + 16)
#define NOM_F (DEN_F + B_N)

// ---------------------------------------------------------------------------
__device__ __forceinline__ ushort f2bf(float f) {
    union { __hip_bfloat16 h; ushort u; } v;
    v.h = __float2bfloat16(f);
    return v.u;
}
__device__ __forceinline__ float bf2f(short s) {
    return __uint_as_float(((uint)(ushort)s) << 16);
}

// global->LDS async staging of a 128x64 bf16 tile, linear LDS dest +
// pre-swizzled global source so reads can XOR-swizzle (T2, m201 pattern).
__device__ __forceinline__ void stage_bf16_tile(
        const ushort* __restrict__ g, int row0, int col0, int ldg,
        ushort* lds, int t) {
    int wid = t >> 6, lane = t & 63;
    #pragma unroll
    for (int i = 0; i < 4; ++i) {
        int p = i * 4096 + wid * 1024 + lane * 16;      // linear byte offset
        int row = p >> 7;
        int colb = (p & 127) ^ ((row & 7) << 4);        // inverse swizzle on src
        const ushort* src = g + (size_t)(row0 + row) * ldg + col0 + (colb >> 1);
        ushort* dst = lds + (i * 4096 + wid * 1024) / 2; // wave-uniform base
        __builtin_amdgcn_global_load_lds(
            (const __attribute__((address_space(1))) unsigned int*)src,
            (__attribute__((address_space(3))) unsigned int*)dst, 16, 0, 0);
    }
}

// ---------------------------------------------------------------------------
__global__ __launch_bounds__(256) void init_kernel(float* __restrict__ ws) {
    int i = blockIdx.x * 256 + threadIdx.x;
    if (i < 16 + 2 * B_N) ws[ACC_F + i] = 0.0f;
}

// ---------------------------------------------------------------------------
__device__ __forceinline__ float block_sum256(float v, float* sred) {
    #pragma unroll
    for (int m = 32; m; m >>= 1) v += __shfl_xor(v, m, 64);
    int lane = threadIdx.x & 63, wid = threadIdx.x >> 6;
    __syncthreads();
    if (lane == 0) sred[wid] = v;
    __syncthreads();
    float s = 0.0f;
    if (threadIdx.x == 0) s = sred[0] + sred[1] + sred[2] + sred[3];
    return s;
}

__global__ __launch_bounds__(256) void small_reduce_kernel(
        const float* __restrict__ y_pred, const float* __restrict__ y_target,
        const float* __restrict__ W_e2, const float* __restrict__ b_e2,
        const float* __restrict__ W_head, const float* __restrict__ b_head,
        float* __restrict__ ws) {
    __shared__ float sred[4];
    int t = threadIdx.x;
    int job = blockIdx.y;
    if (job == 0) {
        float s = 0.0f;
        for (int i = blockIdx.x * 256 + t; i < D_N * D_N; i += gridDim.x * 256) {
            float w = W_e2[i]; s += w * w;
        }
        s = block_sum256(s, sred);
        if (t == 0) atomicAdd(&ws[ACC_F + A_W2], s);
    } else if (job == 1) {
        float s = 0.0f;
        for (int i = blockIdx.x * 256 + t; i < B_N; i += gridDim.x * 256) {
            float d = y_pred[i] - y_target[i]; s += d * d;
        }
        s = block_sum256(s, sred);
        if (t == 0) atomicAdd(&ws[ACC_F + A_MSE], s);
    } else {
        if (blockIdx.x != 0) return;
        float v1 = b_e2[t], v2 = b_e2[t + 256];
        float s = block_sum256(v1 * v1 + v2 * v2, sred);
        if (t == 0) atomicAdd(&ws[ACC_F + A_B2], s);
        v1 = W_head[t]; v2 = W_head[t + 256];
        s = block_sum256(v1 * v1 + v2 * v2, sred);
        if (t == 0) {
            atomicAdd(&ws[ACC_F + A_WH2], s);
            atomicAdd(&ws[ACC_F + A_BH2], b_head[0] * b_head[0]);
        }
    }
}

// ---------------------------------------------------------------------------
// Wtb[n][k] = bf16(W[k][n]) via 64x64 LDS transpose tiles
__global__ __launch_bounds__(256) void wtb_kernel(
        const float* __restrict__ W, ushort* __restrict__ wtb) {
    __shared__ float tile[64][65];
    int k0 = blockIdx.y * 64, n0 = blockIdx.x * 64;
    int t = threadIdx.x;
    int r = t >> 4, c = (t & 15) * 4;
    #pragma unroll
    for (int i = 0; i < 4; ++i) {
        f32x4 v = *(const f32x4*)(W + (size_t)(k0 + r + i * 16) * D_N + n0 + c);
        tile[r + i * 16][c]     = v.x;
        tile[r + i * 16][c + 1] = v.y;
        tile[r + i * 16][c + 2] = v.z;
        tile[r + i * 16][c + 3] = v.w;
    }
    __syncthreads();
    int nl = t >> 2, kq = (t & 3) * 16;
    bf16x8 o0, o1;
    #pragma unroll
    for (int j = 0; j < 8; ++j) o0[j] = (short)f2bf(tile[kq + j][nl]);
    #pragma unroll
    for (int j = 0; j < 8; ++j) o1[j] = (short)f2bf(tile[kq + 8 + j][nl]);
    ushort* dst = wtb + (size_t)(n0 + nl) * D_N + k0 + kq;
    *(bf16x8*)dst = o0;
    *(bf16x8*)(dst + 8) = o1;
}

// ---------------------------------------------------------------------------
__global__ __launch_bounds__(256) void conv_e2b_kernel(
        const float* __restrict__ e2, ushort* __restrict__ e2b) {
    int i = (blockIdx.x * 256 + threadIdx.x) * 8;
    f32x4 v0 = *(const f32x4*)(e2 + i);
    f32x4 v1 = *(const f32x4*)(e2 + i + 4);
    bf16x8 o;
    o[0] = (short)f2bf(v0.x); o[1] = (short)f2bf(v0.y);
    o[2] = (short)f2bf(v0.z); o[3] = (short)f2bf(v0.w);
    o[4] = (short)f2bf(v1.x); o[5] = (short)f2bf(v1.y);
    o[6] = (short)f2bf(v1.z); o[7] = (short)f2bf(v1.w);
    *(bf16x8*)(e2b + i) = o;
}

// ---------------------------------------------------------------------------
// phi = mixup(e1) @ W + b  -> bf16 phib.  MFMA 128x128 tile, BK=64.
// A: reg-staged (mixup fused, swizzled ds_write). B: gload_lds from Wtb.
__global__ __launch_bounds__(256) void phi_kernel(
        const float* __restrict__ e1, const ushort* __restrict__ wtb,
        const float* __restrict__ bvec, const float* __restrict__ lmbda,
        const int* __restrict__ mix, ushort* __restrict__ phib) {
    __shared__ ushort As[128 * 64];
    __shared__ ushort Bs[128 * 64];
    int rb = blockIdx.y * 128, cb = blockIdx.x * 128;
    int t = threadIdx.x;
    int lane = t & 63, wid = t >> 6;
    int l15 = lane & 15, g = lane >> 4, x7 = l15 & 7;
    int wr = wid >> 1, wc = wid & 1;

    // A staging invariants (rows fixed per thread across K)
    int tr = t >> 3, tc = (t & 7) * 8;
    int rloc[4]; float lam[4], oml[4];
    const float *pa[4], *pc[4];
    #pragma unroll
    for (int i = 0; i < 4; ++i) {
        int row = i * 32 + tr;
        rloc[i] = row;
        int grow = rb + row;
        lam[i] = lmbda[grow]; oml[i] = 1.0f - lam[i];
        pa[i] = e1 + (size_t)grow * D_N + tc;
        pc[i] = e1 + (size_t)mix[grow] * D_N + tc;
    }

    f32x4 acc[4][4] = {};
    for (int kk = 0; kk < D_N; kk += 64) {
        __syncthreads();
        stage_bf16_tile(wtb, cb, kk, D_N, Bs, t);
        #pragma unroll
        for (int i = 0; i < 4; ++i) {
            f32x4 a0 = *(const f32x4*)(pa[i] + kk);
            f32x4 a1 = *(const f32x4*)(pa[i] + kk + 4);
            f32x4 c0 = *(const f32x4*)(pc[i] + kk);
            f32x4 c1 = *(const f32x4*)(pc[i] + kk + 4);
            bf16x8 o;
            o[0] = (short)f2bf(lam[i] * a0.x + oml[i] * c0.x);
            o[1] = (short)f2bf(lam[i] * a0.y + oml[i] * c0.y);
            o[2] = (short)f2bf(lam[i] * a0.z + oml[i] * c0.z);
            o[3] = (short)f2bf(lam[i] * a0.w + oml[i] * c0.w);
            o[4] = (short)f2bf(lam[i] * a1.x + oml[i] * c1.x);
            o[5] = (short)f2bf(lam[i] * a1.y + oml[i] * c1.y);
            o[6] = (short)f2bf(lam[i] * a1.z + oml[i] * c1.z);
            o[7] = (short)f2bf(lam[i] * a1.w + oml[i] * c1.w);
            int row = rloc[i];
            int dst = row * 128 + ((tc * 2) ^ ((row & 7) << 4));
            *(bf16x8*)((char*)As + dst) = o;
        }
        __syncthreads();
        bf16x8 a[4][2], b[4][2];
        #pragma unroll
        for (int mi = 0; mi < 4; ++mi)
            #pragma unroll
            for (int ks = 0; ks < 2; ++ks) {
                int ar = wr * 64 + mi * 16 + l15;
                a[mi][ks] = *(const bf16x8*)((const char*)As +
                    ar * 128 + (((ks << 2) | g) ^ x7) * 16);
                int br = wc * 64 + mi * 16 + l15;
                b[mi][ks] = *(const bf16x8*)((const char*)Bs +
                    br * 128 + (((ks << 2) | g) ^ x7) * 16);
            }
        #pragma unroll
        for (int mi = 0; mi < 4; ++mi)
            #pragma unroll
            for (int ni = 0; ni < 4; ++ni)
                #pragma unroll
                for (int ks = 0; ks < 2; ++ks)
                    acc[mi][ni] = __builtin_amdgcn_mfma_f32_16x16x32_bf16(
                        a[mi][ks], b[ni][ks], acc[mi][ni], 0, 0, 0);
    }
    // epilogue: + bias, store bf16
    float bb[4];
    #pragma unroll
    for (int ni = 0; ni < 4; ++ni) bb[ni] = bvec[cb + wc * 64 + ni * 16 + l15];
    #pragma unroll
    for (int mi = 0; mi < 4; ++mi)
        #pragma unroll
        for (int r = 0; r < 4; ++r) {
            int row = rb + wr * 64 + mi * 16 + g * 4 + r;
            #pragma unroll
            for (int ni = 0; ni < 4; ++ni) {
                int col = cb + wc * 64 + ni * 16 + l15;
                phib[(size_t)row * D_N + col] = f2bf(acc[mi][ni][r] + bb[ni]);
            }
        }
}

// ---------------------------------------------------------------------------
// supp: Gram e2b @ e2b^T via MFMA, fused exp row-sum epilogue.
__global__ __launch_bounds__(256) void supp_kernel(
        const ushort* __restrict__ e2b, const int* __restrict__ tag,
        float* __restrict__ ws) {
    __shared__ ushort As[128 * 64];
    __shared__ ushort Bs[128 * 64];
    __shared__ int rt_s[128], ct_s[128];

    int bid = blockIdx.x;
    int sw = (bid & 7) * 128 + (bid >> 3);       // XCD-aware swizzle (1024%8==0)
    int bx = sw & 31, by = sw >> 5;
    int rb = by * 128, cb = bx * 128;
    int t = threadIdx.x;
    if (t < 128) rt_s[t] = tag[rb + t];
    else         ct_s[t - 128] = tag[cb + t - 128];

    int lane = t & 63, wid = t >> 6;
    int l15 = lane & 15, g = lane >> 4, x7 = l15 & 7;
    int wr = wid >> 1, wc = wid & 1;

    f32x4 acc[4][4] = {};
    for (int kk = 0; kk < D_N; kk += 64) {
        __syncthreads();
        stage_bf16_tile(e2b, rb, kk, D_N, As, t);
        stage_bf16_tile(e2b, cb, kk, D_N, Bs, t);
        __syncthreads();                          // drains vmcnt before barrier
        bf16x8 a[4][2], b[4][2];
        #pragma unroll
        for (int mi = 0; mi < 4; ++mi)
            #pragma unroll
            for (int ks = 0; ks < 2; ++ks) {
                int ar = wr * 64 + mi * 16 + l15;
                a[mi][ks] = *(const bf16x8*)((const char*)As +
                    ar * 128 + (((ks << 2) | g) ^ x7) * 16);
                int br = wc * 64 + mi * 16 + l15;
                b[mi][ks] = *(const bf16x8*)((const char*)Bs +
                    br * 128 + (((ks << 2) | g) ^ x7) * 16);
            }
        #pragma unroll
        for (int mi = 0; mi < 4; ++mi)
            #pragma unroll
            for (int ni = 0; ni < 4; ++ni)
                #pragma unroll
                for (int ks = 0; ks < 2; ++ks)
                    acc[mi][ni] = __builtin_amdgcn_mfma_f32_16x16x32_bf16(
                        a[mi][ks], b[ni][ks], acc[mi][ni], 0, 0, 0);
    }
    // epilogue: v = exp(tau*S); den += v; nom += v if diff-domain
    int ct[4];
    #pragma unroll
    for (int ni = 0; ni < 4; ++ni) ct[ni] = ct_s[wc * 64 + ni * 16 + l15];
    #pragma unroll
    for (int mi = 0; mi < 4; ++mi) {
        #pragma unroll
        for (int r = 0; r < 4; ++r) {
            int row = wr * 64 + mi * 16 + g * 4 + r;
            int rt = rt_s[row];
            float d = 0.f, n = 0.f;
            #pragma unroll
            for (int ni = 0; ni < 4; ++ni) {
                float v = __expf(TAU_F * acc[mi][ni][r]);
                d += v;
                if (ct[ni] != rt) n += v;
            }
            #pragma unroll
            for (int mm = 1; mm < 16; mm <<= 1) {
                d += __shfl_xor(d, mm);
                n += __shfl_xor(n, mm);
            }
            if (l15 == 0) {
                atomicAdd(&ws[DEN_F + rb + row], d);
                atomicAdd(&ws[NOM_F + rb + row], n);
            }
        }
    }
}

// ---------------------------------------------------------------------------
// aug: per row j, dots of e2_j (regs) with gathered bf16 phi rows.
__global__ __launch_bounds__(256) void aug_kernel(
        const float* __restrict__ e2, const ushort* __restrict__ phib,
        const int* __restrict__ neg_idx, float* __restrict__ ws) {
    __shared__ float wsum[4];
    int j = blockIdx.x;
    int t = threadIdx.x, lane = t & 63, w = t >> 6;
    f32x4 ea = *(const f32x4*)(e2 + (size_t)j * D_N + lane * 8);
    f32x4 eb = *(const f32x4*)(e2 + (size_t)j * D_N + lane * 8 + 4);
    float negsum = 0.f, pos = 0.f;
    for (int item = w; item < 1 + N_NEGS; item += 4) {
        int tgt = (item == 0) ? j : neg_idx[(size_t)j * N_NEGS + item - 1];
        bf16x8 pv = *(const bf16x8*)(phib + (size_t)tgt * D_N + lane * 8);
        float s = ea.x * bf2f(pv[0]) + ea.y * bf2f(pv[1])
                + ea.z * bf2f(pv[2]) + ea.w * bf2f(pv[3])
                + eb.x * bf2f(pv[4]) + eb.y * bf2f(pv[5])
                + eb.z * bf2f(pv[6]) + eb.w * bf2f(pv[7]);
        #pragma unroll
        for (int mm = 32; mm; mm >>= 1) s += __shfl_xor(s, mm);
        float v = __expf(TAU_F * s);
        if (item == 0) pos = v; else negsum += v;
    }
    if (lane == 0) wsum[w] = negsum;
    __syncthreads();
    if (t == 0) {
        float ns = wsum[0] + wsum[1] + wsum[2] + wsum[3];
        float L = logf(pos / (EPS_F + pos + ns));
        if (L == L) atomicAdd(&ws[ACC_F + A_AUG], L);
    }
}

// ---------------------------------------------------------------------------
__global__ __launch_bounds__(256) void finalize_kernel(
        const float* __restrict__ ws, const int* __restrict__ tag,
        float* __restrict__ out) {
    __shared__ int cnt[N_DOM];
    __shared__ float sred[4];
    int t = threadIdx.x;
    if (t < N_DOM) cnt[t] = 0;
    __syncthreads();
    for (int i = t; i < B_N; i += 256) atomicAdd(&cnt[tag[i]], 1);
    __syncthreads();
    float local = 0.0f;
    for (int i = t; i < B_N; i += 256) {
        float den = ws[DEN_F + i], nom = ws[NOM_F + i];
        float L = logf(nom / (den + EPS_F));
        bool valid = (cnt[tag[i]] < B_N) && (L == L);
        if (valid) local += L;
    }
    float s = block_sum256(local, sred);
    if (t == 0) {
        out[0] = ws[ACC_F + A_MSE] / (float)B_N;
        out[1] = REGW_F * (sqrtf(ws[ACC_F + A_W2]) + sqrtf(ws[ACC_F + A_B2]) +
                           sqrtf(ws[ACC_F + A_WH2]) + sqrtf(ws[ACC_F + A_BH2]));
        out[2] = -ws[ACC_F + A_AUG] / (float)B_N;
        out[3] = -s / (float)B_N;
    }
}

// ---------------------------------------------------------------------------
extern "C" void kernel_launch(void* const* d_in, const int* in_sizes, int n_in,
                              void* d_out, int out_size, void* d_ws, size_t ws_size,
                              hipStream_t stream) {
    const float* e1       = (const float*)d_in[0];
    const float* e2       = (const float*)d_in[1];
    const float* y_pred   = (const float*)d_in[2];
    const float* y_target = (const float*)d_in[3];
    const float* W_e2     = (const float*)d_in[4];
    const float* b_e2     = (const float*)d_in[5];
    const float* W_head   = (const float*)d_in[6];
    const float* b_head   = (const float*)d_in[7];
    const float* lmbda    = (const float*)d_in[8];
    const int*   mix_idx  = (const int*)d_in[9];
    const int*   neg_idx  = (const int*)d_in[10];
    const int*   dtag     = (const int*)d_in[11];
    float* ws  = (float*)d_ws;
    float* out = (float*)d_out;
    ushort* phib = (ushort*)(ws + PHIB_F);
    ushort* xbuf = (ushort*)(ws + X_F);     // Wtb during phi, e2b afterwards

    init_kernel<<<dim3(33), dim3(256), 0, stream>>>(ws);
    small_reduce_kernel<<<dim3(128, 3), dim3(256), 0, stream>>>(
        y_pred, y_target, W_e2, b_e2, W_head, b_head, ws);
    wtb_kernel<<<dim3(8, 8), dim3(256), 0, stream>>>(W_e2, xbuf);
    phi_kernel<<<dim3(D_N / 128, B_N / 128), dim3(256), 0, stream>>>(
        e1, xbuf, b_e2, lmbda, mix_idx, phib);
    conv_e2b_kernel<<<dim3(1024), dim3(256), 0, stream>>>(e2, xbuf);  // overwrites Wtb (done)
    supp_kernel<<<dim3(1024), dim3(256), 0, stream>>>(xbuf, dtag, ws);
    aug_kernel<<<dim3(B_N), dim3(256), 0, stream>>>(e2, phib, neg_idx, ws);
    finalize_kernel<<<dim3(1), dim3(256), 0, stream>>>(ws, dtag, out);
}

// Round 3
// 135.934 us; speedup vs baseline: 2.9508x; 1.1905x over previous
//
#include <hip/hip_runtime.h>
#include <hip/hip_bf16.h>
#include <math.h>

#define B_N 4096
#define D_N 512
#define N_NEGS 100
#define N_DOM 8
#define TAU_F 1e-4f
#define EPS_F 1e-6f
#define REGW_F 1e-4f

typedef __attribute__((ext_vector_type(8))) short bf16x8;
typedef __attribute__((ext_vector_type(4))) float f32x4;

// ---- workspace layout (float index offsets). Total = 8,421,440 bytes.
#define PHIB_F 0                       // bf16 phi [4096][512]  (4 MB)
#define X_F    (B_N * D_N / 2)         // region X: Wtb (phi phase) then e2b
#define ACC_F  (B_N * D_N)             // scalar accumulators
#define A_MSE 0
#define A_W2  1
#define A_B2  2
#define A_WH2 3
#define A_BH2 4
#define A_AUG 5
#define DEN_F (ACC_F + 16)
#define NOM_F (DEN_F + B_N)

// ---------------------------------------------------------------------------
__device__ __forceinline__ ushort f2bf(float f) {
    union { __hip_bfloat16 h; ushort u; } v;
    v.h = __float2bfloat16(f);
    return v.u;
}
__device__ __forceinline__ float bf2f(short s) {
    return __uint_as_float(((uint)(ushort)s) << 16);
}

// global->LDS async staging of a 128x64 bf16 tile, linear LDS dest +
// pre-swizzled global source so reads can XOR-swizzle (T2, m201 pattern).
__device__ __forceinline__ void stage_bf16_tile(
        const ushort* __restrict__ g, int row0, int col0, int ldg,
        ushort* lds, int t) {
    int wid = t >> 6, lane = t & 63;
    #pragma unroll
    for (int i = 0; i < 4; ++i) {
        int p = i * 4096 + wid * 1024 + lane * 16;      // linear byte offset
        int row = p >> 7;
        int colb = (p & 127) ^ ((row & 7) << 4);        // inverse swizzle on src
        const ushort* src = g + (size_t)(row0 + row) * ldg + col0 + (colb >> 1);
        ushort* dst = lds + (i * 4096 + wid * 1024) / 2; // wave-uniform base
        __builtin_amdgcn_global_load_lds(
            (const __attribute__((address_space(1))) unsigned int*)src,
            (__attribute__((address_space(3))) unsigned int*)dst, 16, 0, 0);
    }
}

// ---------------------------------------------------------------------------
__global__ __launch_bounds__(256) void init_kernel(float* __restrict__ ws) {
    int i = blockIdx.x * 256 + threadIdx.x;
    if (i < 16 + 2 * B_N) ws[ACC_F + i] = 0.0f;
}

// ---------------------------------------------------------------------------
__device__ __forceinline__ float block_sum256(float v, float* sred) {
    #pragma unroll
    for (int m = 32; m; m >>= 1) v += __shfl_xor(v, m, 64);
    int lane = threadIdx.x & 63, wid = threadIdx.x >> 6;
    __syncthreads();
    if (lane == 0) sred[wid] = v;
    __syncthreads();
    float s = 0.0f;
    if (threadIdx.x == 0) s = sred[0] + sred[1] + sred[2] + sred[3];
    return s;
}

__global__ __launch_bounds__(256) void small_reduce_kernel(
        const float* __restrict__ y_pred, const float* __restrict__ y_target,
        const float* __restrict__ W_e2, const float* __restrict__ b_e2,
        const float* __restrict__ W_head, const float* __restrict__ b_head,
        float* __restrict__ ws) {
    __shared__ float sred[4];
    int t = threadIdx.x;
    int job = blockIdx.y;
    if (job == 0) {
        float s = 0.0f;
        for (int i = blockIdx.x * 256 + t; i < D_N * D_N; i += gridDim.x * 256) {
            float w = W_e2[i]; s += w * w;
        }
        s = block_sum256(s, sred);
        if (t == 0) atomicAdd(&ws[ACC_F + A_W2], s);
    } else if (job == 1) {
        float s = 0.0f;
        for (int i = blockIdx.x * 256 + t; i < B_N; i += gridDim.x * 256) {
            float d = y_pred[i] - y_target[i]; s += d * d;
        }
        s = block_sum256(s, sred);
        if (t == 0) atomicAdd(&ws[ACC_F + A_MSE], s);
    } else {
        if (blockIdx.x != 0) return;
        float v1 = b_e2[t], v2 = b_e2[t + 256];
        float s = block_sum256(v1 * v1 + v2 * v2, sred);
        if (t == 0) atomicAdd(&ws[ACC_F + A_B2], s);
        v1 = W_head[t]; v2 = W_head[t + 256];
        s = block_sum256(v1 * v1 + v2 * v2, sred);
        if (t == 0) {
            atomicAdd(&ws[ACC_F + A_WH2], s);
            atomicAdd(&ws[ACC_F + A_BH2], b_head[0] * b_head[0]);
        }
    }
}

// ---------------------------------------------------------------------------
// Wtb[n][k] = bf16(W[k][n]) via 64x64 LDS transpose tiles
__global__ __launch_bounds__(256) void wtb_kernel(
        const float* __restrict__ W, ushort* __restrict__ wtb) {
    __shared__ float tile[64][65];
    int k0 = blockIdx.y * 64, n0 = blockIdx.x * 64;
    int t = threadIdx.x;
    int r = t >> 4, c = (t & 15) * 4;
    #pragma unroll
    for (int i = 0; i < 4; ++i) {
        f32x4 v = *(const f32x4*)(W + (size_t)(k0 + r + i * 16) * D_N + n0 + c);
        tile[r + i * 16][c]     = v.x;
        tile[r + i * 16][c + 1] = v.y;
        tile[r + i * 16][c + 2] = v.z;
        tile[r + i * 16][c + 3] = v.w;
    }
    __syncthreads();
    int nl = t >> 2, kq = (t & 3) * 16;
    bf16x8 o0, o1;
    #pragma unroll
    for (int j = 0; j < 8; ++j) o0[j] = (short)f2bf(tile[kq + j][nl]);
    #pragma unroll
    for (int j = 0; j < 8; ++j) o1[j] = (short)f2bf(tile[kq + 8 + j][nl]);
    ushort* dst = wtb + (size_t)(n0 + nl) * D_N + k0 + kq;
    *(bf16x8*)dst = o0;
    *(bf16x8*)(dst + 8) = o1;
}

// ---------------------------------------------------------------------------
__global__ __launch_bounds__(256) void conv_e2b_kernel(
        const float* __restrict__ e2, ushort* __restrict__ e2b) {
    int i = (blockIdx.x * 256 + threadIdx.x) * 8;
    f32x4 v0 = *(const f32x4*)(e2 + i);
    f32x4 v1 = *(const f32x4*)(e2 + i + 4);
    bf16x8 o;
    o[0] = (short)f2bf(v0.x); o[1] = (short)f2bf(v0.y);
    o[2] = (short)f2bf(v0.z); o[3] = (short)f2bf(v0.w);
    o[4] = (short)f2bf(v1.x); o[5] = (short)f2bf(v1.y);
    o[6] = (short)f2bf(v1.z); o[7] = (short)f2bf(v1.w);
    *(bf16x8*)(e2b + i) = o;
}

// ---------------------------------------------------------------------------
// phi = mixup(e1) @ W + b  -> bf16 phib.  MFMA 128x128 tile, BK=64.
__global__ __launch_bounds__(256) void phi_kernel(
        const float* __restrict__ e1, const ushort* __restrict__ wtb,
        const float* __restrict__ bvec, const float* __restrict__ lmbda,
        const int* __restrict__ mix, ushort* __restrict__ phib) {
    __shared__ ushort As[128 * 64];
    __shared__ ushort Bs[128 * 64];
    int rb = blockIdx.y * 128, cb = blockIdx.x * 128;
    int t = threadIdx.x;
    int lane = t & 63, wid = t >> 6;
    int l15 = lane & 15, g = lane >> 4, x7 = l15 & 7;
    int wr = wid >> 1, wc = wid & 1;

    int tr = t >> 3, tc = (t & 7) * 8;
    int rloc[4]; float lam[4], oml[4];
    const float *pa[4], *pc[4];
    #pragma unroll
    for (int i = 0; i < 4; ++i) {
        int row = i * 32 + tr;
        rloc[i] = row;
        int grow = rb + row;
        lam[i] = lmbda[grow]; oml[i] = 1.0f - lam[i];
        pa[i] = e1 + (size_t)grow * D_N + tc;
        pc[i] = e1 + (size_t)mix[grow] * D_N + tc;
    }

    f32x4 acc[4][4] = {};
    for (int kk = 0; kk < D_N; kk += 64) {
        __syncthreads();
        stage_bf16_tile(wtb, cb, kk, D_N, Bs, t);
        #pragma unroll
        for (int i = 0; i < 4; ++i) {
            f32x4 a0 = *(const f32x4*)(pa[i] + kk);
            f32x4 a1 = *(const f32x4*)(pa[i] + kk + 4);
            f32x4 c0 = *(const f32x4*)(pc[i] + kk);
            f32x4 c1 = *(const f32x4*)(pc[i] + kk + 4);
            bf16x8 o;
            o[0] = (short)f2bf(lam[i] * a0.x + oml[i] * c0.x);
            o[1] = (short)f2bf(lam[i] * a0.y + oml[i] * c0.y);
            o[2] = (short)f2bf(lam[i] * a0.z + oml[i] * c0.z);
            o[3] = (short)f2bf(lam[i] * a0.w + oml[i] * c0.w);
            o[4] = (short)f2bf(lam[i] * a1.x + oml[i] * c1.x);
            o[5] = (short)f2bf(lam[i] * a1.y + oml[i] * c1.y);
            o[6] = (short)f2bf(lam[i] * a1.z + oml[i] * c1.z);
            o[7] = (short)f2bf(lam[i] * a1.w + oml[i] * c1.w);
            int row = rloc[i];
            int dst = row * 128 + ((tc * 2) ^ ((row & 7) << 4));
            *(bf16x8*)((char*)As + dst) = o;
        }
        __syncthreads();
        bf16x8 a[4][2], b[4][2];
        #pragma unroll
        for (int mi = 0; mi < 4; ++mi)
            #pragma unroll
            for (int ks = 0; ks < 2; ++ks) {
                int ar = wr * 64 + mi * 16 + l15;
                a[mi][ks] = *(const bf16x8*)((const char*)As +
                    ar * 128 + (((ks << 2) | g) ^ x7) * 16);
                int br = wc * 64 + mi * 16 + l15;
                b[mi][ks] = *(const bf16x8*)((const char*)Bs +
                    br * 128 + (((ks << 2) | g) ^ x7) * 16);
            }
        #pragma unroll
        for (int mi = 0; mi < 4; ++mi)
            #pragma unroll
            for (int ni = 0; ni < 4; ++ni)
                #pragma unroll
                for (int ks = 0; ks < 2; ++ks)
                    acc[mi][ni] = __builtin_amdgcn_mfma_f32_16x16x32_bf16(
                        a[mi][ks], b[ni][ks], acc[mi][ni], 0, 0, 0);
    }
    float bb[4];
    #pragma unroll
    for (int ni = 0; ni < 4; ++ni) bb[ni] = bvec[cb + wc * 64 + ni * 16 + l15];
    #pragma unroll
    for (int mi = 0; mi < 4; ++mi)
        #pragma unroll
        for (int r = 0; r < 4; ++r) {
            int row = rb + wr * 64 + mi * 16 + g * 4 + r;
            #pragma unroll
            for (int ni = 0; ni < 4; ++ni) {
                int col = cb + wc * 64 + ni * 16 + l15;
                phib[(size_t)row * D_N + col] = f2bf(acc[mi][ni][r] + bb[ni]);
            }
        }
}

// ---------------------------------------------------------------------------
// supp: symmetric Gram -> only lower-triangle tiles (bx<=by).
// Off-diagonal tiles emit row-sums AND column-sums (via symmetry).
__global__ __launch_bounds__(256) void supp_kernel(
        const ushort* __restrict__ e2b, const int* __restrict__ tag,
        float* __restrict__ ws) {
    __shared__ ushort As[128 * 64];
    __shared__ ushort Bs[128 * 64];
    __shared__ int rt_s[128], ct_s[128];

    int tid = blockIdx.x;                      // 0..527
    int sw = (tid & 7) * 66 + (tid >> 3);      // XCD swizzle (528 = 8*66)
    int by = (int)((sqrtf(8.0f * (float)sw + 1.0f) - 1.0f) * 0.5f);
    while ((by + 1) * (by + 2) / 2 <= sw) ++by;
    while (by * (by + 1) / 2 > sw) --by;
    int bx = sw - by * (by + 1) / 2;           // bx <= by
    bool diag = (bx == by);
    int rb = by * 128, cb = bx * 128;
    int t = threadIdx.x;
    if (t < 128) rt_s[t] = tag[rb + t];
    else         ct_s[t - 128] = tag[cb + t - 128];

    int lane = t & 63, wid = t >> 6;
    int l15 = lane & 15, g = lane >> 4, x7 = l15 & 7;
    int wr = wid >> 1, wc = wid & 1;

    f32x4 acc[4][4] = {};
    for (int kk = 0; kk < D_N; kk += 64) {
        __syncthreads();
        stage_bf16_tile(e2b, rb, kk, D_N, As, t);
        stage_bf16_tile(e2b, cb, kk, D_N, Bs, t);
        __syncthreads();
        bf16x8 a[4][2], b[4][2];
        #pragma unroll
        for (int mi = 0; mi < 4; ++mi)
            #pragma unroll
            for (int ks = 0; ks < 2; ++ks) {
                int ar = wr * 64 + mi * 16 + l15;
                a[mi][ks] = *(const bf16x8*)((const char*)As +
                    ar * 128 + (((ks << 2) | g) ^ x7) * 16);
                int br = wc * 64 + mi * 16 + l15;
                b[mi][ks] = *(const bf16x8*)((const char*)Bs +
                    br * 128 + (((ks << 2) | g) ^ x7) * 16);
            }
        #pragma unroll
        for (int mi = 0; mi < 4; ++mi)
            #pragma unroll
            for (int ni = 0; ni < 4; ++ni)
                #pragma unroll
                for (int ks = 0; ks < 2; ++ks)
                    acc[mi][ni] = __builtin_amdgcn_mfma_f32_16x16x32_bf16(
                        a[mi][ks], b[ni][ks], acc[mi][ni], 0, 0, 0);
    }
    int ct[4];
    #pragma unroll
    for (int ni = 0; ni < 4; ++ni) ct[ni] = ct_s[wc * 64 + ni * 16 + l15];
    float cd[4] = {}, cn[4] = {};
    #pragma unroll
    for (int mi = 0; mi < 4; ++mi) {
        #pragma unroll
        for (int r = 0; r < 4; ++r) {
            int row = wr * 64 + mi * 16 + g * 4 + r;
            int rt = rt_s[row];
            float d = 0.f, n = 0.f;
            #pragma unroll
            for (int ni = 0; ni < 4; ++ni) {
                float v = __expf(TAU_F * acc[mi][ni][r]);
                float nv = (ct[ni] != rt) ? v : 0.f;
                d += v; n += nv;
                cd[ni] += v; cn[ni] += nv;
            }
            #pragma unroll
            for (int mm = 1; mm < 16; mm <<= 1) {
                d += __shfl_xor(d, mm);
                n += __shfl_xor(n, mm);
            }
            if (l15 == 0) {
                atomicAdd(&ws[DEN_F + rb + row], d);
                atomicAdd(&ws[NOM_F + rb + row], n);
            }
        }
    }
    if (!diag) {
        #pragma unroll
        for (int ni = 0; ni < 4; ++ni) {
            float d = cd[ni], n = cn[ni];
            d += __shfl_xor(d, 16); d += __shfl_xor(d, 32);
            n += __shfl_xor(n, 16); n += __shfl_xor(n, 32);
            if (g == 0) {
                int col = wc * 64 + ni * 16 + l15;
                atomicAdd(&ws[DEN_F + cb + col], d);
                atomicAdd(&ws[NOM_F + cb + col], n);
            }
        }
    }
}

// ---------------------------------------------------------------------------
// aug: 4 lanes per item, dot accumulated in registers (no per-item wave
// reduce chain). Block = 512 threads covers all 101 items in one pass.
__global__ __launch_bounds__(512) void aug_kernel(
        const float* __restrict__ e2, const ushort* __restrict__ phib,
        const int* __restrict__ neg_idx, float* __restrict__ ws) {
    __shared__ float e2s[D_N];
    __shared__ float wred[8];
    __shared__ float spos;
    int j = blockIdx.x;
    int t = threadIdx.x;
    if (t < 128)
        *(f32x4*)&e2s[t * 4] = *(const f32x4*)(e2 + (size_t)j * D_N + t * 4);
    __syncthreads();
    int item = t >> 2, sub = t & 3;
    float s = 0.f;
    if (item < 1 + N_NEGS) {
        int tgt = (item == 0) ? j : neg_idx[(size_t)j * N_NEGS + item - 1];
        const ushort* p = phib + (size_t)tgt * D_N + sub * 8;
        const float* es = e2s + sub * 8;
        #pragma unroll
        for (int k = 0; k < 16; ++k) {
            bf16x8 pv = *(const bf16x8*)(p + k * 32);
            f32x4 e0 = *(const f32x4*)(es + k * 32);
            f32x4 e1v = *(const f32x4*)(es + k * 32 + 4);
            s += e0.x  * bf2f(pv[0]) + e0.y  * bf2f(pv[1])
               + e0.z  * bf2f(pv[2]) + e0.w  * bf2f(pv[3])
               + e1v.x * bf2f(pv[4]) + e1v.y * bf2f(pv[5])
               + e1v.z * bf2f(pv[6]) + e1v.w * bf2f(pv[7]);
        }
    }
    s += __shfl_xor(s, 1);
    s += __shfl_xor(s, 2);
    float v = __expf(TAU_F * s);
    if (t == 0) spos = v;
    float contrib = (sub == 0 && item >= 1 && item < 1 + N_NEGS) ? v : 0.f;
    #pragma unroll
    for (int mm = 4; mm < 64; mm <<= 1) contrib += __shfl_xor(contrib, mm);
    int lane = t & 63, w = t >> 6;
    if (lane == 0) wred[w] = contrib;
    __syncthreads();
    if (t == 0) {
        float ns = wred[0] + wred[1] + wred[2] + wred[3]
                 + wred[4] + wred[5] + wred[6] + wred[7];
        float pos = spos;
        float L = logf(pos / (EPS_F + pos + ns));
        if (L == L) atomicAdd(&ws[ACC_F + A_AUG], L);
    }
}

// ---------------------------------------------------------------------------
__global__ __launch_bounds__(256) void finalize_kernel(
        const float* __restrict__ ws, const int* __restrict__ tag,
        float* __restrict__ out) {
    __shared__ int cnt[N_DOM];
    __shared__ float sred[4];
    int t = threadIdx.x;
    if (t < N_DOM) cnt[t] = 0;
    __syncthreads();
    for (int i = t; i < B_N; i += 256) atomicAdd(&cnt[tag[i]], 1);
    __syncthreads();
    float local = 0.0f;
    for (int i = t; i < B_N; i += 256) {
        float den = ws[DEN_F + i], nom = ws[NOM_F + i];
        float L = logf(nom / (den + EPS_F));
        bool valid = (cnt[tag[i]] < B_N) && (L == L);
        if (valid) local += L;
    }
    float s = block_sum256(local, sred);
    if (t == 0) {
        out[0] = ws[ACC_F + A_MSE] / (float)B_N;
        out[1] = REGW_F * (sqrtf(ws[ACC_F + A_W2]) + sqrtf(ws[ACC_F + A_B2]) +
                           sqrtf(ws[ACC_F + A_WH2]) + sqrtf(ws[ACC_F + A_BH2]));
        out[2] = -ws[ACC_F + A_AUG] / (float)B_N;
        out[3] = -s / (float)B_N;
    }
}

// ---------------------------------------------------------------------------
extern "C" void kernel_launch(void* const* d_in, const int* in_sizes, int n_in,
                              void* d_out, int out_size, void* d_ws, size_t ws_size,
                              hipStream_t stream) {
    const float* e1       = (const float*)d_in[0];
    const float* e2       = (const float*)d_in[1];
    const float* y_pred   = (const float*)d_in[2];
    const float* y_target = (const float*)d_in[3];
    const float* W_e2     = (const float*)d_in[4];
    const float* b_e2     = (const float*)d_in[5];
    const float* W_head   = (const float*)d_in[6];
    const float* b_head   = (const float*)d_in[7];
    const float* lmbda    = (const float*)d_in[8];
    const int*   mix_idx  = (const int*)d_in[9];
    const int*   neg_idx  = (const int*)d_in[10];
    const int*   dtag     = (const int*)d_in[11];
    float* ws  = (float*)d_ws;
    float* out = (float*)d_out;
    ushort* phib = (ushort*)(ws + PHIB_F);
    ushort* xbuf = (ushort*)(ws + X_F);     // Wtb during phi, e2b afterwards

    init_kernel<<<dim3(33), dim3(256), 0, stream>>>(ws);
    small_reduce_kernel<<<dim3(128, 3), dim3(256), 0, stream>>>(
        y_pred, y_target, W_e2, b_e2, W_head, b_head, ws);
    wtb_kernel<<<dim3(8, 8), dim3(256), 0, stream>>>(W_e2, xbuf);
    phi_kernel<<<dim3(D_N / 128, B_N / 128), dim3(256), 0, stream>>>(
        e1, xbuf, b_e2, lmbda, mix_idx, phib);
    conv_e2b_kernel<<<dim3(1024), dim3(256), 0, stream>>>(e2, xbuf);
    supp_kernel<<<dim3(528), dim3(256), 0, stream>>>(xbuf, dtag, ws);
    aug_kernel<<<dim3(B_N), dim3(512), 0, stream>>>(e2, phib, neg_idx, ws);
    finalize_kernel<<<dim3(1), dim3(256), 0, stream>>>(ws, dtag, out);
}

// Round 4
// 133.759 us; speedup vs baseline: 2.9988x; 1.0163x over previous
//
#include <hip/hip_runtime.h>
#include <hip/hip_bf16.h>
#include <math.h>

#define B_N 4096
#define D_N 512
#define N_NEGS 100
#define N_DOM 8
#define TAU_F 1e-4f
#define EPS_F 1e-6f
#define REGW_F 1e-4f

typedef __attribute__((ext_vector_type(8))) short bf16x8;
typedef __attribute__((ext_vector_type(4))) float f32x4;

// ---- workspace layout (float index offsets). Total = 8,421,440 bytes.
#define PHIB_F 0                       // bf16 phi [4096][512]  (4 MB)
#define X_F    (B_N * D_N / 2)         // region X: Wtb (phi phase) then e2b
#define ACC_F  (B_N * D_N)             // scalar accumulators
#define A_MSE 0
#define A_W2  1
#define A_B2  2
#define A_WH2 3
#define A_BH2 4
#define A_AUG 5
#define DEN_F (ACC_F + 16)
#define NOM_F (DEN_F + B_N)

// ---------------------------------------------------------------------------
__device__ __forceinline__ ushort f2bf(float f) {
    union { __hip_bfloat16 h; ushort u; } v;
    v.h = __float2bfloat16(f);
    return v.u;
}
__device__ __forceinline__ float bf2f(short s) {
    return __uint_as_float(((uint)(ushort)s) << 16);
}

// global->LDS async staging of a 128x64 bf16 tile, linear LDS dest +
// pre-swizzled global source so reads can XOR-swizzle (T2, m201 pattern).
__device__ __forceinline__ void stage_bf16_tile(
        const ushort* __restrict__ g, int row0, int col0, int ldg,
        ushort* lds, int t) {
    int wid = t >> 6, lane = t & 63;
    #pragma unroll
    for (int i = 0; i < 4; ++i) {
        int p = i * 4096 + wid * 1024 + lane * 16;      // linear byte offset
        int row = p >> 7;
        int colb = (p & 127) ^ ((row & 7) << 4);        // inverse swizzle on src
        const ushort* src = g + (size_t)(row0 + row) * ldg + col0 + (colb >> 1);
        ushort* dst = lds + (i * 4096 + wid * 1024) / 2; // wave-uniform base
        __builtin_amdgcn_global_load_lds(
            (const __attribute__((address_space(1))) unsigned int*)src,
            (__attribute__((address_space(3))) unsigned int*)dst, 16, 0, 0);
    }
}

// ---------------------------------------------------------------------------
__global__ __launch_bounds__(256) void init_kernel(float* __restrict__ ws) {
    int i = blockIdx.x * 256 + threadIdx.x;
    if (i < 16 + 2 * B_N) ws[ACC_F + i] = 0.0f;
}

// ---------------------------------------------------------------------------
__device__ __forceinline__ float block_sum256(float v, float* sred) {
    #pragma unroll
    for (int m = 32; m; m >>= 1) v += __shfl_xor(v, m, 64);
    int lane = threadIdx.x & 63, wid = threadIdx.x >> 6;
    __syncthreads();
    if (lane == 0) sred[wid] = v;
    __syncthreads();
    float s = 0.0f;
    if (threadIdx.x == 0) s = sred[0] + sred[1] + sred[2] + sred[3];
    return s;
}

__global__ __launch_bounds__(256) void small_reduce_kernel(
        const float* __restrict__ y_pred, const float* __restrict__ y_target,
        const float* __restrict__ W_e2, const float* __restrict__ b_e2,
        const float* __restrict__ W_head, const float* __restrict__ b_head,
        float* __restrict__ ws) {
    __shared__ float sred[4];
    int t = threadIdx.x;
    int job = blockIdx.y;
    if (job == 0) {
        float s = 0.0f;
        for (int i = blockIdx.x * 256 + t; i < D_N * D_N; i += gridDim.x * 256) {
            float w = W_e2[i]; s += w * w;
        }
        s = block_sum256(s, sred);
        if (t == 0) atomicAdd(&ws[ACC_F + A_W2], s);
    } else if (job == 1) {
        float s = 0.0f;
        for (int i = blockIdx.x * 256 + t; i < B_N; i += gridDim.x * 256) {
            float d = y_pred[i] - y_target[i]; s += d * d;
        }
        s = block_sum256(s, sred);
        if (t == 0) atomicAdd(&ws[ACC_F + A_MSE], s);
    } else {
        if (blockIdx.x != 0) return;
        float v1 = b_e2[t], v2 = b_e2[t + 256];
        float s = block_sum256(v1 * v1 + v2 * v2, sred);
        if (t == 0) atomicAdd(&ws[ACC_F + A_B2], s);
        v1 = W_head[t]; v2 = W_head[t + 256];
        s = block_sum256(v1 * v1 + v2 * v2, sred);
        if (t == 0) {
            atomicAdd(&ws[ACC_F + A_WH2], s);
            atomicAdd(&ws[ACC_F + A_BH2], b_head[0] * b_head[0]);
        }
    }
}

// ---------------------------------------------------------------------------
// Wtb[n][k] = bf16(W[k][n]) via 64x64 LDS transpose tiles
__global__ __launch_bounds__(256) void wtb_kernel(
        const float* __restrict__ W, ushort* __restrict__ wtb) {
    __shared__ float tile[64][65];
    int k0 = blockIdx.y * 64, n0 = blockIdx.x * 64;
    int t = threadIdx.x;
    int r = t >> 4, c = (t & 15) * 4;
    #pragma unroll
    for (int i = 0; i < 4; ++i) {
        f32x4 v = *(const f32x4*)(W + (size_t)(k0 + r + i * 16) * D_N + n0 + c);
        tile[r + i * 16][c]     = v.x;
        tile[r + i * 16][c + 1] = v.y;
        tile[r + i * 16][c + 2] = v.z;
        tile[r + i * 16][c + 3] = v.w;
    }
    __syncthreads();
    int nl = t >> 2, kq = (t & 3) * 16;
    bf16x8 o0, o1;
    #pragma unroll
    for (int j = 0; j < 8; ++j) o0[j] = (short)f2bf(tile[kq + j][nl]);
    #pragma unroll
    for (int j = 0; j < 8; ++j) o1[j] = (short)f2bf(tile[kq + 8 + j][nl]);
    ushort* dst = wtb + (size_t)(n0 + nl) * D_N + k0 + kq;
    *(bf16x8*)dst = o0;
    *(bf16x8*)(dst + 8) = o1;
}

// ---------------------------------------------------------------------------
__global__ __launch_bounds__(256) void conv_e2b_kernel(
        const float* __restrict__ e2, ushort* __restrict__ e2b) {
    int i = (blockIdx.x * 256 + threadIdx.x) * 8;
    f32x4 v0 = *(const f32x4*)(e2 + i);
    f32x4 v1 = *(const f32x4*)(e2 + i + 4);
    bf16x8 o;
    o[0] = (short)f2bf(v0.x); o[1] = (short)f2bf(v0.y);
    o[2] = (short)f2bf(v0.z); o[3] = (short)f2bf(v0.w);
    o[4] = (short)f2bf(v1.x); o[5] = (short)f2bf(v1.y);
    o[6] = (short)f2bf(v1.z); o[7] = (short)f2bf(v1.w);
    *(bf16x8*)(e2b + i) = o;
}

// ---------------------------------------------------------------------------
// phi = mixup(e1) @ W + b  -> bf16 phib.  MFMA 128x128 tile, BK=64.
__global__ __launch_bounds__(256) void phi_kernel(
        const float* __restrict__ e1, const ushort* __restrict__ wtb,
        const float* __restrict__ bvec, const float* __restrict__ lmbda,
        const int* __restrict__ mix, ushort* __restrict__ phib) {
    __shared__ ushort As[128 * 64];
    __shared__ ushort Bs[128 * 64];
    int rb = blockIdx.y * 128, cb = blockIdx.x * 128;
    int t = threadIdx.x;
    int lane = t & 63, wid = t >> 6;
    int l15 = lane & 15, g = lane >> 4, x7 = l15 & 7;
    int wr = wid >> 1, wc = wid & 1;

    int tr = t >> 3, tc = (t & 7) * 8;
    int rloc[4]; float lam[4], oml[4];
    const float *pa[4], *pc[4];
    #pragma unroll
    for (int i = 0; i < 4; ++i) {
        int row = i * 32 + tr;
        rloc[i] = row;
        int grow = rb + row;
        lam[i] = lmbda[grow]; oml[i] = 1.0f - lam[i];
        pa[i] = e1 + (size_t)grow * D_N + tc;
        pc[i] = e1 + (size_t)mix[grow] * D_N + tc;
    }

    f32x4 acc[4][4] = {};
    for (int kk = 0; kk < D_N; kk += 64) {
        __syncthreads();
        stage_bf16_tile(wtb, cb, kk, D_N, Bs, t);
        #pragma unroll
        for (int i = 0; i < 4; ++i) {
            f32x4 a0 = *(const f32x4*)(pa[i] + kk);
            f32x4 a1 = *(const f32x4*)(pa[i] + kk + 4);
            f32x4 c0 = *(const f32x4*)(pc[i] + kk);
            f32x4 c1 = *(const f32x4*)(pc[i] + kk + 4);
            bf16x8 o;
            o[0] = (short)f2bf(lam[i] * a0.x + oml[i] * c0.x);
            o[1] = (short)f2bf(lam[i] * a0.y + oml[i] * c0.y);
            o[2] = (short)f2bf(lam[i] * a0.z + oml[i] * c0.z);
            o[3] = (short)f2bf(lam[i] * a0.w + oml[i] * c0.w);
            o[4] = (short)f2bf(lam[i] * a1.x + oml[i] * c1.x);
            o[5] = (short)f2bf(lam[i] * a1.y + oml[i] * c1.y);
            o[6] = (short)f2bf(lam[i] * a1.z + oml[i] * c1.z);
            o[7] = (short)f2bf(lam[i] * a1.w + oml[i] * c1.w);
            int row = rloc[i];
            int dst = row * 128 + ((tc * 2) ^ ((row & 7) << 4));
            *(bf16x8*)((char*)As + dst) = o;
        }
        __syncthreads();
        bf16x8 a[4][2], b[4][2];
        #pragma unroll
        for (int mi = 0; mi < 4; ++mi)
            #pragma unroll
            for (int ks = 0; ks < 2; ++ks) {
                int ar = wr * 64 + mi * 16 + l15;
                a[mi][ks] = *(const bf16x8*)((const char*)As +
                    ar * 128 + (((ks << 2) | g) ^ x7) * 16);
                int br = wc * 64 + mi * 16 + l15;
                b[mi][ks] = *(const bf16x8*)((const char*)Bs +
                    br * 128 + (((ks << 2) | g) ^ x7) * 16);
            }
        #pragma unroll
        for (int mi = 0; mi < 4; ++mi)
            #pragma unroll
            for (int ni = 0; ni < 4; ++ni)
                #pragma unroll
                for (int ks = 0; ks < 2; ++ks)
                    acc[mi][ni] = __builtin_amdgcn_mfma_f32_16x16x32_bf16(
                        a[mi][ks], b[ni][ks], acc[mi][ni], 0, 0, 0);
    }
    float bb[4];
    #pragma unroll
    for (int ni = 0; ni < 4; ++ni) bb[ni] = bvec[cb + wc * 64 + ni * 16 + l15];
    #pragma unroll
    for (int mi = 0; mi < 4; ++mi)
        #pragma unroll
        for (int r = 0; r < 4; ++r) {
            int row = rb + wr * 64 + mi * 16 + g * 4 + r;
            #pragma unroll
            for (int ni = 0; ni < 4; ++ni) {
                int col = cb + wc * 64 + ni * 16 + l15;
                phib[(size_t)row * D_N + col] = f2bf(acc[mi][ni][r] + bb[ni]);
            }
        }
}

// ---------------------------------------------------------------------------
// supp: symmetric Gram -> only lower-triangle tiles (bx<=by).
// Off-diagonal tiles emit row-sums AND column-sums (via symmetry).
__global__ __launch_bounds__(256) void supp_kernel(
        const ushort* __restrict__ e2b, const int* __restrict__ tag,
        float* __restrict__ ws) {
    __shared__ ushort As[128 * 64];
    __shared__ ushort Bs[128 * 64];
    __shared__ int rt_s[128], ct_s[128];

    int tid = blockIdx.x;                      // 0..527
    int sw = (tid & 7) * 66 + (tid >> 3);      // XCD swizzle (528 = 8*66)
    int by = (int)((sqrtf(8.0f * (float)sw + 1.0f) - 1.0f) * 0.5f);
    while ((by + 1) * (by + 2) / 2 <= sw) ++by;
    while (by * (by + 1) / 2 > sw) --by;
    int bx = sw - by * (by + 1) / 2;           // bx <= by
    bool diag = (bx == by);
    int rb = by * 128, cb = bx * 128;
    int t = threadIdx.x;
    if (t < 128) rt_s[t] = tag[rb + t];
    else         ct_s[t - 128] = tag[cb + t - 128];

    int lane = t & 63, wid = t >> 6;
    int l15 = lane & 15, g = lane >> 4, x7 = l15 & 7;
    int wr = wid >> 1, wc = wid & 1;

    f32x4 acc[4][4] = {};
    for (int kk = 0; kk < D_N; kk += 64) {
        __syncthreads();
        stage_bf16_tile(e2b, rb, kk, D_N, As, t);
        stage_bf16_tile(e2b, cb, kk, D_N, Bs, t);
        __syncthreads();
        bf16x8 a[4][2], b[4][2];
        #pragma unroll
        for (int mi = 0; mi < 4; ++mi)
            #pragma unroll
            for (int ks = 0; ks < 2; ++ks) {
                int ar = wr * 64 + mi * 16 + l15;
                a[mi][ks] = *(const bf16x8*)((const char*)As +
                    ar * 128 + (((ks << 2) | g) ^ x7) * 16);
                int br = wc * 64 + mi * 16 + l15;
                b[mi][ks] = *(const bf16x8*)((const char*)Bs +
                    br * 128 + (((ks << 2) | g) ^ x7) * 16);
            }
        #pragma unroll
        for (int mi = 0; mi < 4; ++mi)
            #pragma unroll
            for (int ni = 0; ni < 4; ++ni)
                #pragma unroll
                for (int ks = 0; ks < 2; ++ks)
                    acc[mi][ni] = __builtin_amdgcn_mfma_f32_16x16x32_bf16(
                        a[mi][ks], b[ni][ks], acc[mi][ni], 0, 0, 0);
    }
    int ct[4];
    #pragma unroll
    for (int ni = 0; ni < 4; ++ni) ct[ni] = ct_s[wc * 64 + ni * 16 + l15];
    float cd[4] = {}, cn[4] = {};
    #pragma unroll
    for (int mi = 0; mi < 4; ++mi) {
        #pragma unroll
        for (int r = 0; r < 4; ++r) {
            int row = wr * 64 + mi * 16 + g * 4 + r;
            int rt = rt_s[row];
            float d = 0.f, n = 0.f;
            #pragma unroll
            for (int ni = 0; ni < 4; ++ni) {
                float v = __expf(TAU_F * acc[mi][ni][r]);
                float nv = (ct[ni] != rt) ? v : 0.f;
                d += v; n += nv;
                cd[ni] += v; cn[ni] += nv;
            }
            #pragma unroll
            for (int mm = 1; mm < 16; mm <<= 1) {
                d += __shfl_xor(d, mm);
                n += __shfl_xor(n, mm);
            }
            if (l15 == 0) {
                atomicAdd(&ws[DEN_F + rb + row], d);
                atomicAdd(&ws[NOM_F + rb + row], n);
            }
        }
    }
    if (!diag) {
        #pragma unroll
        for (int ni = 0; ni < 4; ++ni) {
            float d = cd[ni], n = cn[ni];
            d += __shfl_xor(d, 16); d += __shfl_xor(d, 32);
            n += __shfl_xor(n, 16); n += __shfl_xor(n, 32);
            if (g == 0) {
                int col = wc * 64 + ni * 16 + l15;
                atomicAdd(&ws[DEN_F + cb + col], d);
                atomicAdd(&ws[NOM_F + cb + col], n);
            }
        }
    }
}

// ---------------------------------------------------------------------------
// aug: 8 lanes per item, all 101 items in one 1024-thread block.
// All 8 gather loads prefetched into registers (static indexing -> VGPRs),
// two independent accumulators to break the FMA dependency chain.
__global__ __launch_bounds__(1024) void aug_kernel(
        const float* __restrict__ e2, const ushort* __restrict__ phib,
        const int* __restrict__ neg_idx, float* __restrict__ ws) {
    __shared__ float e2s[D_N];
    __shared__ float wred[16];
    __shared__ float spos;
    int j = blockIdx.x;
    int t = threadIdx.x;
    if (t < 128)
        *(f32x4*)&e2s[t * 4] = *(const f32x4*)(e2 + (size_t)j * D_N + t * 4);
    __syncthreads();

    int item = t >> 3, sub = t & 7;          // 128 item slots, 101 active
    bool active = item < 1 + N_NEGS;
    int tgt = j;
    if (active && item > 0) tgt = neg_idx[(size_t)j * N_NEGS + item - 1];
    const ushort* p = phib + (size_t)tgt * D_N + sub * 8;

    // prefetch: 8 independent 16B loads, statically indexed
    bf16x8 pv[8];
    #pragma unroll
    for (int k = 0; k < 8; ++k) pv[k] = *(const bf16x8*)(p + k * 64);

    const float* es = e2s + sub * 8;
    float s0 = 0.f, s1 = 0.f;
    #pragma unroll
    for (int k = 0; k < 8; ++k) {
        f32x4 e0  = *(const f32x4*)(es + k * 64);
        f32x4 e1v = *(const f32x4*)(es + k * 64 + 4);
        s0 += e0.x  * bf2f(pv[k][0]) + e0.y  * bf2f(pv[k][1])
            + e0.z  * bf2f(pv[k][2]) + e0.w  * bf2f(pv[k][3]);
        s1 += e1v.x * bf2f(pv[k][4]) + e1v.y * bf2f(pv[k][5])
            + e1v.z * bf2f(pv[k][6]) + e1v.w * bf2f(pv[k][7]);
    }
    float s = s0 + s1;
    s += __shfl_xor(s, 1);
    s += __shfl_xor(s, 2);
    s += __shfl_xor(s, 4);                    // 8-lane group sum
    float v = active ? __expf(TAU_F * s) : 0.f;
    if (t == 0) spos = v;
    float contrib = (sub == 0 && item >= 1 && active) ? v : 0.f;
    contrib += __shfl_xor(contrib, 8);
    contrib += __shfl_xor(contrib, 16);
    contrib += __shfl_xor(contrib, 32);       // wave sum (8 items/wave)
    int lane = t & 63, w = t >> 6;
    if (lane == 0) wred[w] = contrib;
    __syncthreads();
    if (t == 0) {
        float ns = 0.f;
        #pragma unroll
        for (int i = 0; i < 16; ++i) ns += wred[i];
        float pos = spos;
        float L = logf(pos / (EPS_F + pos + ns));
        if (L == L) atomicAdd(&ws[ACC_F + A_AUG], L);
    }
}

// ---------------------------------------------------------------------------
__global__ __launch_bounds__(256) void finalize_kernel(
        const float* __restrict__ ws, const int* __restrict__ tag,
        float* __restrict__ out) {
    __shared__ int cnt[N_DOM];
    __shared__ float sred[4];
    int t = threadIdx.x;
    if (t < N_DOM) cnt[t] = 0;
    __syncthreads();
    for (int i = t; i < B_N; i += 256) atomicAdd(&cnt[tag[i]], 1);
    __syncthreads();
    float local = 0.0f;
    for (int i = t; i < B_N; i += 256) {
        float den = ws[DEN_F + i], nom = ws[NOM_F + i];
        float L = logf(nom / (den + EPS_F));
        bool valid = (cnt[tag[i]] < B_N) && (L == L);
        if (valid) local += L;
    }
    float s = block_sum256(local, sred);
    if (t == 0) {
        out[0] = ws[ACC_F + A_MSE] / (float)B_N;
        out[1] = REGW_F * (sqrtf(ws[ACC_F + A_W2]) + sqrtf(ws[ACC_F + A_B2]) +
                           sqrtf(ws[ACC_F + A_WH2]) + sqrtf(ws[ACC_F + A_BH2]));
        out[2] = -ws[ACC_F + A_AUG] / (float)B_N;
        out[3] = -s / (float)B_N;
    }
}

// ---------------------------------------------------------------------------
extern "C" void kernel_launch(void* const* d_in, const int* in_sizes, int n_in,
                              void* d_out, int out_size, void* d_ws, size_t ws_size,
                              hipStream_t stream) {
    const float* e1       = (const float*)d_in[0];
    const float* e2       = (const float*)d_in[1];
    const float* y_pred   = (const float*)d_in[2];
    const float* y_target = (const float*)d_in[3];
    const float* W_e2     = (const float*)d_in[4];
    const float* b_e2     = (const float*)d_in[5];
    const float* W_head   = (const float*)d_in[6];
    const float* b_head   = (const float*)d_in[7];
    const float* lmbda    = (const float*)d_in[8];
    const int*   mix_idx  = (const int*)d_in[9];
    const int*   neg_idx  = (const int*)d_in[10];
    const int*   dtag     = (const int*)d_in[11];
    float* ws  = (float*)d_ws;
    float* out = (float*)d_out;
    ushort* phib = (ushort*)(ws + PHIB_F);
    ushort* xbuf = (ushort*)(ws + X_F);     // Wtb during phi, e2b afterwards

    init_kernel<<<dim3(33), dim3(256), 0, stream>>>(ws);
    small_reduce_kernel<<<dim3(128, 3), dim3(256), 0, stream>>>(
        y_pred, y_target, W_e2, b_e2, W_head, b_head, ws);
    wtb_kernel<<<dim3(8, 8), dim3(256), 0, stream>>>(W_e2, xbuf);
    phi_kernel<<<dim3(D_N / 128, B_N / 128), dim3(256), 0, stream>>>(
        e1, xbuf, b_e2, lmbda, mix_idx, phib);
    conv_e2b_kernel<<<dim3(1024), dim3(256), 0, stream>>>(e2, xbuf);
    supp_kernel<<<dim3(528), dim3(256), 0, stream>>>(xbuf, dtag, ws);
    aug_kernel<<<dim3(B_N), dim3(1024), 0, stream>>>(e2, phib, neg_idx, ws);
    finalize_kernel<<<dim3(1), dim3(256), 0, stream>>>(ws, dtag, out);
}

// Round 5
// 123.129 us; speedup vs baseline: 3.2577x; 1.0863x over previous
//
#include <hip/hip_runtime.h>
#include <hip/hip_bf16.h>
#include <math.h>

#define B_N 4096
#define D_N 512
#define N_NEGS 100
#define N_DOM 8
#define TAU_F 1e-4f
#define EPS_F 1e-6f
#define REGW_F 1e-4f
#define ITEMS_J 101
#define SEXP_LD 102

typedef __attribute__((ext_vector_type(8))) short bf16x8;
typedef __attribute__((ext_vector_type(4))) float f32x4;

// ---- workspace layout (float index offsets). Total = 8,421,440 bytes.
#define PHIB_F 0                       // bf16 phi [4096][512]  (4 MB)
#define X_F    (B_N * D_N / 2)         // region X: Wtb -> e2b -> sexp (serial reuse)
#define ACC_F  (B_N * D_N)             // scalar accumulators
#define A_MSE 0
#define A_W2  1
#define A_B2  2
#define A_WH2 3
#define A_BH2 4
#define A_AUG 5
#define DEN_F (ACC_F + 16)
#define NOM_F (DEN_F + B_N)

// ---------------------------------------------------------------------------
__device__ __forceinline__ ushort f2bf(float f) {
    union { __hip_bfloat16 h; ushort u; } v;
    v.h = __float2bfloat16(f);
    return v.u;
}
__device__ __forceinline__ float bf2f(short s) {
    return __uint_as_float(((uint)(ushort)s) << 16);
}

// global->LDS async staging of a 128x64 bf16 tile, linear LDS dest +
// pre-swizzled global source so reads can XOR-swizzle (T2, m201 pattern).
__device__ __forceinline__ void stage_bf16_tile(
        const ushort* __restrict__ g, int row0, int col0, int ldg,
        ushort* lds, int t) {
    int wid = t >> 6, lane = t & 63;
    #pragma unroll
    for (int i = 0; i < 4; ++i) {
        int p = i * 4096 + wid * 1024 + lane * 16;      // linear byte offset
        int row = p >> 7;
        int colb = (p & 127) ^ ((row & 7) << 4);        // inverse swizzle on src
        const ushort* src = g + (size_t)(row0 + row) * ldg + col0 + (colb >> 1);
        ushort* dst = lds + (i * 4096 + wid * 1024) / 2; // wave-uniform base
        __builtin_amdgcn_global_load_lds(
            (const __attribute__((address_space(1))) unsigned int*)src,
            (__attribute__((address_space(3))) unsigned int*)dst, 16, 0, 0);
    }
}

// ---------------------------------------------------------------------------
__global__ __launch_bounds__(256) void init_kernel(float* __restrict__ ws) {
    int i = blockIdx.x * 256 + threadIdx.x;
    if (i < 16 + 2 * B_N) ws[ACC_F + i] = 0.0f;
}

// ---------------------------------------------------------------------------
__device__ __forceinline__ float block_sum256(float v, float* sred) {
    #pragma unroll
    for (int m = 32; m; m >>= 1) v += __shfl_xor(v, m, 64);
    int lane = threadIdx.x & 63, wid = threadIdx.x >> 6;
    __syncthreads();
    if (lane == 0) sred[wid] = v;
    __syncthreads();
    float s = 0.0f;
    if (threadIdx.x == 0) s = sred[0] + sred[1] + sred[2] + sred[3];
    return s;
}

__global__ __launch_bounds__(256) void small_reduce_kernel(
        const float* __restrict__ y_pred, const float* __restrict__ y_target,
        const float* __restrict__ W_e2, const float* __restrict__ b_e2,
        const float* __restrict__ W_head, const float* __restrict__ b_head,
        float* __restrict__ ws) {
    __shared__ float sred[4];
    int t = threadIdx.x;
    int job = blockIdx.y;
    if (job == 0) {
        float s = 0.0f;
        for (int i = blockIdx.x * 256 + t; i < D_N * D_N; i += gridDim.x * 256) {
            float w = W_e2[i]; s += w * w;
        }
        s = block_sum256(s, sred);
        if (t == 0) atomicAdd(&ws[ACC_F + A_W2], s);
    } else if (job == 1) {
        float s = 0.0f;
        for (int i = blockIdx.x * 256 + t; i < B_N; i += gridDim.x * 256) {
            float d = y_pred[i] - y_target[i]; s += d * d;
        }
        s = block_sum256(s, sred);
        if (t == 0) atomicAdd(&ws[ACC_F + A_MSE], s);
    } else {
        if (blockIdx.x != 0) return;
        float v1 = b_e2[t], v2 = b_e2[t + 256];
        float s = block_sum256(v1 * v1 + v2 * v2, sred);
        if (t == 0) atomicAdd(&ws[ACC_F + A_B2], s);
        v1 = W_head[t]; v2 = W_head[t + 256];
        s = block_sum256(v1 * v1 + v2 * v2, sred);
        if (t == 0) {
            atomicAdd(&ws[ACC_F + A_WH2], s);
            atomicAdd(&ws[ACC_F + A_BH2], b_head[0] * b_head[0]);
        }
    }
}

// ---------------------------------------------------------------------------
// Wtb[n][k] = bf16(W[k][n]) via 64x64 LDS transpose tiles
__global__ __launch_bounds__(256) void wtb_kernel(
        const float* __restrict__ W, ushort* __restrict__ wtb) {
    __shared__ float tile[64][65];
    int k0 = blockIdx.y * 64, n0 = blockIdx.x * 64;
    int t = threadIdx.x;
    int r = t >> 4, c = (t & 15) * 4;
    #pragma unroll
    for (int i = 0; i < 4; ++i) {
        f32x4 v = *(const f32x4*)(W + (size_t)(k0 + r + i * 16) * D_N + n0 + c);
        tile[r + i * 16][c]     = v.x;
        tile[r + i * 16][c + 1] = v.y;
        tile[r + i * 16][c + 2] = v.z;
        tile[r + i * 16][c + 3] = v.w;
    }
    __syncthreads();
    int nl = t >> 2, kq = (t & 3) * 16;
    bf16x8 o0, o1;
    #pragma unroll
    for (int j = 0; j < 8; ++j) o0[j] = (short)f2bf(tile[kq + j][nl]);
    #pragma unroll
    for (int j = 0; j < 8; ++j) o1[j] = (short)f2bf(tile[kq + 8 + j][nl]);
    ushort* dst = wtb + (size_t)(n0 + nl) * D_N + k0 + kq;
    *(bf16x8*)dst = o0;
    *(bf16x8*)(dst + 8) = o1;
}

// ---------------------------------------------------------------------------
__global__ __launch_bounds__(256) void conv_e2b_kernel(
        const float* __restrict__ e2, ushort* __restrict__ e2b) {
    int i = (blockIdx.x * 256 + threadIdx.x) * 8;
    f32x4 v0 = *(const f32x4*)(e2 + i);
    f32x4 v1 = *(const f32x4*)(e2 + i + 4);
    bf16x8 o;
    o[0] = (short)f2bf(v0.x); o[1] = (short)f2bf(v0.y);
    o[2] = (short)f2bf(v0.z); o[3] = (short)f2bf(v0.w);
    o[4] = (short)f2bf(v1.x); o[5] = (short)f2bf(v1.y);
    o[6] = (short)f2bf(v1.z); o[7] = (short)f2bf(v1.w);
    *(bf16x8*)(e2b + i) = o;
}

// ---------------------------------------------------------------------------
// phi = mixup(e1) @ W + b  -> bf16 phib.  MFMA 128x128 tile, BK=64.
__global__ __launch_bounds__(256) void phi_kernel(
        const float* __restrict__ e1, const ushort* __restrict__ wtb,
        const float* __restrict__ bvec, const float* __restrict__ lmbda,
        const int* __restrict__ mix, ushort* __restrict__ phib) {
    __shared__ ushort As[128 * 64];
    __shared__ ushort Bs[128 * 64];
    int rb = blockIdx.y * 128, cb = blockIdx.x * 128;
    int t = threadIdx.x;
    int lane = t & 63, wid = t >> 6;
    int l15 = lane & 15, g = lane >> 4, x7 = l15 & 7;
    int wr = wid >> 1, wc = wid & 1;

    int tr = t >> 3, tc = (t & 7) * 8;
    int rloc[4]; float lam[4], oml[4];
    const float *pa[4], *pc[4];
    #pragma unroll
    for (int i = 0; i < 4; ++i) {
        int row = i * 32 + tr;
        rloc[i] = row;
        int grow = rb + row;
        lam[i] = lmbda[grow]; oml[i] = 1.0f - lam[i];
        pa[i] = e1 + (size_t)grow * D_N + tc;
        pc[i] = e1 + (size_t)mix[grow] * D_N + tc;
    }

    f32x4 acc[4][4] = {};
    for (int kk = 0; kk < D_N; kk += 64) {
        __syncthreads();
        stage_bf16_tile(wtb, cb, kk, D_N, Bs, t);
        #pragma unroll
        for (int i = 0; i < 4; ++i) {
            f32x4 a0 = *(const f32x4*)(pa[i] + kk);
            f32x4 a1 = *(const f32x4*)(pa[i] + kk + 4);
            f32x4 c0 = *(const f32x4*)(pc[i] + kk);
            f32x4 c1 = *(const f32x4*)(pc[i] + kk + 4);
            bf16x8 o;
            o[0] = (short)f2bf(lam[i] * a0.x + oml[i] * c0.x);
            o[1] = (short)f2bf(lam[i] * a0.y + oml[i] * c0.y);
            o[2] = (short)f2bf(lam[i] * a0.z + oml[i] * c0.z);
            o[3] = (short)f2bf(lam[i] * a0.w + oml[i] * c0.w);
            o[4] = (short)f2bf(lam[i] * a1.x + oml[i] * c1.x);
            o[5] = (short)f2bf(lam[i] * a1.y + oml[i] * c1.y);
            o[6] = (short)f2bf(lam[i] * a1.z + oml[i] * c1.z);
            o[7] = (short)f2bf(lam[i] * a1.w + oml[i] * c1.w);
            int row = rloc[i];
            int dst = row * 128 + ((tc * 2) ^ ((row & 7) << 4));
            *(bf16x8*)((char*)As + dst) = o;
        }
        __syncthreads();
        bf16x8 a[4][2], b[4][2];
        #pragma unroll
        for (int mi = 0; mi < 4; ++mi)
            #pragma unroll
            for (int ks = 0; ks < 2; ++ks) {
                int ar = wr * 64 + mi * 16 + l15;
                a[mi][ks] = *(const bf16x8*)((const char*)As +
                    ar * 128 + (((ks << 2) | g) ^ x7) * 16);
                int br = wc * 64 + mi * 16 + l15;
                b[mi][ks] = *(const bf16x8*)((const char*)Bs +
                    br * 128 + (((ks << 2) | g) ^ x7) * 16);
            }
        #pragma unroll
        for (int mi = 0; mi < 4; ++mi)
            #pragma unroll
            for (int ni = 0; ni < 4; ++ni)
                #pragma unroll
                for (int ks = 0; ks < 2; ++ks)
                    acc[mi][ni] = __builtin_amdgcn_mfma_f32_16x16x32_bf16(
                        a[mi][ks], b[ni][ks], acc[mi][ni], 0, 0, 0);
    }
    float bb[4];
    #pragma unroll
    for (int ni = 0; ni < 4; ++ni) bb[ni] = bvec[cb + wc * 64 + ni * 16 + l15];
    #pragma unroll
    for (int mi = 0; mi < 4; ++mi)
        #pragma unroll
        for (int r = 0; r < 4; ++r) {
            int row = rb + wr * 64 + mi * 16 + g * 4 + r;
            #pragma unroll
            for (int ni = 0; ni < 4; ++ni) {
                int col = cb + wc * 64 + ni * 16 + l15;
                phib[(size_t)row * D_N + col] = f2bf(acc[mi][ni][r] + bb[ni]);
            }
        }
}

// ---------------------------------------------------------------------------
// supp: symmetric Gram -> only lower-triangle tiles (bx<=by).
__global__ __launch_bounds__(256) void supp_kernel(
        const ushort* __restrict__ e2b, const int* __restrict__ tag,
        float* __restrict__ ws) {
    __shared__ ushort As[128 * 64];
    __shared__ ushort Bs[128 * 64];
    __shared__ int rt_s[128], ct_s[128];

    int tid = blockIdx.x;                      // 0..527
    int sw = (tid & 7) * 66 + (tid >> 3);      // XCD swizzle (528 = 8*66)
    int by = (int)((sqrtf(8.0f * (float)sw + 1.0f) - 1.0f) * 0.5f);
    while ((by + 1) * (by + 2) / 2 <= sw) ++by;
    while (by * (by + 1) / 2 > sw) --by;
    int bx = sw - by * (by + 1) / 2;           // bx <= by
    bool diag = (bx == by);
    int rb = by * 128, cb = bx * 128;
    int t = threadIdx.x;
    if (t < 128) rt_s[t] = tag[rb + t];
    else         ct_s[t - 128] = tag[cb + t - 128];

    int lane = t & 63, wid = t >> 6;
    int l15 = lane & 15, g = lane >> 4, x7 = l15 & 7;
    int wr = wid >> 1, wc = wid & 1;

    f32x4 acc[4][4] = {};
    for (int kk = 0; kk < D_N; kk += 64) {
        __syncthreads();
        stage_bf16_tile(e2b, rb, kk, D_N, As, t);
        stage_bf16_tile(e2b, cb, kk, D_N, Bs, t);
        __syncthreads();
        bf16x8 a[4][2], b[4][2];
        #pragma unroll
        for (int mi = 0; mi < 4; ++mi)
            #pragma unroll
            for (int ks = 0; ks < 2; ++ks) {
                int ar = wr * 64 + mi * 16 + l15;
                a[mi][ks] = *(const bf16x8*)((const char*)As +
                    ar * 128 + (((ks << 2) | g) ^ x7) * 16);
                int br = wc * 64 + mi * 16 + l15;
                b[mi][ks] = *(const bf16x8*)((const char*)Bs +
                    br * 128 + (((ks << 2) | g) ^ x7) * 16);
            }
        #pragma unroll
        for (int mi = 0; mi < 4; ++mi)
            #pragma unroll
            for (int ni = 0; ni < 4; ++ni)
                #pragma unroll
                for (int ks = 0; ks < 2; ++ks)
                    acc[mi][ni] = __builtin_amdgcn_mfma_f32_16x16x32_bf16(
                        a[mi][ks], b[ni][ks], acc[mi][ni], 0, 0, 0);
    }
    int ct[4];
    #pragma unroll
    for (int ni = 0; ni < 4; ++ni) ct[ni] = ct_s[wc * 64 + ni * 16 + l15];
    float cd[4] = {}, cn[4] = {};
    #pragma unroll
    for (int mi = 0; mi < 4; ++mi) {
        #pragma unroll
        for (int r = 0; r < 4; ++r) {
            int row = wr * 64 + mi * 16 + g * 4 + r;
            int rt = rt_s[row];
            float d = 0.f, n = 0.f;
            #pragma unroll
            for (int ni = 0; ni < 4; ++ni) {
                float v = __expf(TAU_F * acc[mi][ni][r]);
                float nv = (ct[ni] != rt) ? v : 0.f;
                d += v; n += nv;
                cd[ni] += v; cn[ni] += nv;
            }
            #pragma unroll
            for (int mm = 1; mm < 16; mm <<= 1) {
                d += __shfl_xor(d, mm);
                n += __shfl_xor(n, mm);
            }
            if (l15 == 0) {
                atomicAdd(&ws[DEN_F + rb + row], d);
                atomicAdd(&ws[NOM_F + rb + row], n);
            }
        }
    }
    if (!diag) {
        #pragma unroll
        for (int ni = 0; ni < 4; ++ni) {
            float d = cd[ni], n = cn[ni];
            d += __shfl_xor(d, 16); d += __shfl_xor(d, 32);
            n += __shfl_xor(n, 16); n += __shfl_xor(n, 32);
            if (g == 0) {
                int col = wc * 64 + ni * 16 + l15;
                atomicAdd(&ws[DEN_F + cb + col], d);
                atomicAdd(&ws[NOM_F + cb + col], n);
            }
        }
    }
}

// ---------------------------------------------------------------------------
// aug phase A: one 8-lane group per (j,item). No LDS, no barriers, no atomics.
// j-major item order -> adjacent groups share the e2 row (L1/L2 hits).
__global__ __launch_bounds__(256) void aug_dots_kernel(
        const float* __restrict__ e2, const ushort* __restrict__ phib,
        const int* __restrict__ neg_idx, float* __restrict__ sexp) {
    int gi = blockIdx.x * 32 + (threadIdx.x >> 3);   // global item id
    int sub = threadIdx.x & 7;
    int j = gi / ITEMS_J;
    int idx = gi - j * ITEMS_J;
    int tgt = (idx == 0) ? j : neg_idx[(size_t)j * N_NEGS + idx - 1];
    const float*  e = e2   + (size_t)j   * D_N + sub * 8;
    const ushort* p = phib + (size_t)tgt * D_N + sub * 8;
    float s0 = 0.f, s1 = 0.f;
    #pragma unroll
    for (int k = 0; k < 8; ++k) {
        bf16x8 pv = *(const bf16x8*)(p + k * 64);
        f32x4 e0  = *(const f32x4*)(e + k * 64);
        f32x4 e1v = *(const f32x4*)(e + k * 64 + 4);
        s0 += e0.x  * bf2f(pv[0]) + e0.y  * bf2f(pv[1])
            + e0.z  * bf2f(pv[2]) + e0.w  * bf2f(pv[3]);
        s1 += e1v.x * bf2f(pv[4]) + e1v.y * bf2f(pv[5])
            + e1v.z * bf2f(pv[6]) + e1v.w * bf2f(pv[7]);
    }
    float s = s0 + s1;
    s += __shfl_xor(s, 1);
    s += __shfl_xor(s, 2);
    s += __shfl_xor(s, 4);
    if (sub == 0) sexp[(size_t)j * SEXP_LD + idx] = __expf(TAU_F * s);
}

// ---------------------------------------------------------------------------
// aug phase B: one wave per j (grid-stride), 64 block-level atomics total.
__global__ __launch_bounds__(256) void aug_final_kernel(
        const float* __restrict__ sexp, float* __restrict__ ws) {
    __shared__ float wred[4];
    int lane = threadIdx.x & 63, w = threadIdx.x >> 6;
    int wglob = blockIdx.x * 4 + w;
    float acc = 0.f;
    for (int j = wglob; j < B_N; j += 256) {
        float v0 = sexp[(size_t)j * SEXP_LD + lane];
        float v1 = (lane + 64 < ITEMS_J) ? sexp[(size_t)j * SEXP_LD + lane + 64] : 0.f;
        float pos = __shfl(v0, 0);
        float ns = ((lane >= 1) ? v0 : 0.f) + v1;
        #pragma unroll
        for (int mm = 32; mm; mm >>= 1) ns += __shfl_xor(ns, mm);
        if (lane == 0) {
            float L = logf(pos / (EPS_F + pos + ns));
            if (L == L) acc += L;
        }
    }
    if (lane == 0) wred[w] = acc;
    __syncthreads();
    if (threadIdx.x == 0)
        atomicAdd(&ws[ACC_F + A_AUG], wred[0] + wred[1] + wred[2] + wred[3]);
}

// ---------------------------------------------------------------------------
__global__ __launch_bounds__(256) void finalize_kernel(
        const float* __restrict__ ws, const int* __restrict__ tag,
        float* __restrict__ out) {
    __shared__ int cnt[N_DOM];
    __shared__ float sred[4];
    int t = threadIdx.x;
    if (t < N_DOM) cnt[t] = 0;
    __syncthreads();
    for (int i = t; i < B_N; i += 256) atomicAdd(&cnt[tag[i]], 1);
    __syncthreads();
    float local = 0.0f;
    for (int i = t; i < B_N; i += 256) {
        float den = ws[DEN_F + i], nom = ws[NOM_F + i];
        float L = logf(nom / (den + EPS_F));
        bool valid = (cnt[tag[i]] < B_N) && (L == L);
        if (valid) local += L;
    }
    float s = block_sum256(local, sred);
    if (t == 0) {
        out[0] = ws[ACC_F + A_MSE] / (float)B_N;
        out[1] = REGW_F * (sqrtf(ws[ACC_F + A_W2]) + sqrtf(ws[ACC_F + A_B2]) +
                           sqrtf(ws[ACC_F + A_WH2]) + sqrtf(ws[ACC_F + A_BH2]));
        out[2] = -ws[ACC_F + A_AUG] / (float)B_N;
        out[3] = -s / (float)B_N;
    }
}

// ---------------------------------------------------------------------------
extern "C" void kernel_launch(void* const* d_in, const int* in_sizes, int n_in,
                              void* d_out, int out_size, void* d_ws, size_t ws_size,
                              hipStream_t stream) {
    const float* e1       = (const float*)d_in[0];
    const float* e2       = (const float*)d_in[1];
    const float* y_pred   = (const float*)d_in[2];
    const float* y_target = (const float*)d_in[3];
    const float* W_e2     = (const float*)d_in[4];
    const float* b_e2     = (const float*)d_in[5];
    const float* W_head   = (const float*)d_in[6];
    const float* b_head   = (const float*)d_in[7];
    const float* lmbda    = (const float*)d_in[8];
    const int*   mix_idx  = (const int*)d_in[9];
    const int*   neg_idx  = (const int*)d_in[10];
    const int*   dtag     = (const int*)d_in[11];
    float* ws  = (float*)d_ws;
    float* out = (float*)d_out;
    ushort* phib = (ushort*)(ws + PHIB_F);
    ushort* xbuf = (ushort*)(ws + X_F);     // Wtb -> e2b -> sexp (stream-serial)
    float*  sexp = (float*)(ws + X_F);

    init_kernel<<<dim3(33), dim3(256), 0, stream>>>(ws);
    small_reduce_kernel<<<dim3(128, 3), dim3(256), 0, stream>>>(
        y_pred, y_target, W_e2, b_e2, W_head, b_head, ws);
    wtb_kernel<<<dim3(8, 8), dim3(256), 0, stream>>>(W_e2, xbuf);
    phi_kernel<<<dim3(D_N / 128, B_N / 128), dim3(256), 0, stream>>>(
        e1, xbuf, b_e2, lmbda, mix_idx, phib);
    conv_e2b_kernel<<<dim3(1024), dim3(256), 0, stream>>>(e2, xbuf);
    supp_kernel<<<dim3(528), dim3(256), 0, stream>>>(xbuf, dtag, ws);
    aug_dots_kernel<<<dim3(B_N * ITEMS_J / 32), dim3(256), 0, stream>>>(
        e2, phib, neg_idx, sexp);                   // overwrites e2b (supp done)
    aug_final_kernel<<<dim3(64), dim3(256), 0, stream>>>(sexp, ws);
    finalize_kernel<<<dim3(1), dim3(256), 0, stream>>>(ws, dtag, out);
}